// Round 1
// baseline (1067.149 us; speedup 1.0000x reference)
//
#include <hip/hip_runtime.h>
#include <hip/hip_bf16.h>
#include <stdint.h>

#define NBATCH 8
#define CH 256
#define SS 9216
#define EPS 1e-5f

// ---------------- ws layout (bytes) ----------------
// [0, 2048)            : scale[256], shift[256] fp32
// [4096, 4096+2MB)     : kv fp32  [8][256][256]
// [2101248, +4MB)      : Acomb fp32 [8][256][512]  ( [Wp^T | Wp^T @ KV^T] )
// [6295552, +113.25MB) : qkv bf16 [8][768][9216]   (j: 0..255=Q, 256..511=K, 512..767=V)
#define KV_BYTE_OFF   4096
#define AC_BYTE_OFF   2101248
#define QKV_BYTE_OFF  6295552

__device__ inline void bf8_to_f(uint4 p, float* o) {
    o[0] = __uint_as_float(p.x << 16); o[1] = __uint_as_float(p.x & 0xffff0000u);
    o[2] = __uint_as_float(p.y << 16); o[3] = __uint_as_float(p.y & 0xffff0000u);
    o[4] = __uint_as_float(p.z << 16); o[5] = __uint_as_float(p.z & 0xffff0000u);
    o[6] = __uint_as_float(p.w << 16); o[7] = __uint_as_float(p.w & 0xffff0000u);
}

// ---------------- Stage 1: BN stats -> scale/shift ----------------
__global__ __launch_bounds__(256)
void bn_stats(const float* __restrict__ inp, const float* __restrict__ gamma,
              const float* __restrict__ beta, float* __restrict__ sc_sh) {
    const int c = blockIdx.x;
    const int tid = threadIdx.x;
    float sum = 0.f, sumsq = 0.f;
    for (int n = 0; n < NBATCH; ++n) {
        const float* p = inp + ((size_t)(n * CH + c)) * SS;
        for (int s = tid; s < SS; s += 256) {
            float v = p[s];
            sum += v; sumsq += v * v;
        }
    }
    #pragma unroll
    for (int off = 32; off > 0; off >>= 1) {
        sum   += __shfl_down(sum, off, 64);
        sumsq += __shfl_down(sumsq, off, 64);
    }
    __shared__ float ssum[4], ssq[4];
    const int wave = tid >> 6, lane = tid & 63;
    if (lane == 0) { ssum[wave] = sum; ssq[wave] = sumsq; }
    __syncthreads();
    if (tid == 0) {
        float s0 = ssum[0] + ssum[1] + ssum[2] + ssum[3];
        float q0 = ssq[0] + ssq[1] + ssq[2] + ssq[3];
        const float invN = 1.0f / (float)(NBATCH * SS);
        float m = s0 * invN;
        float var = q0 * invN - m * m;
        float rstd = rsqrtf(var + EPS);
        float sc = gamma[c] * rstd;
        sc_sh[c] = sc;
        sc_sh[CH + c] = beta[c] - m * sc;
    }
}

// ---------------- Stage 2: QKV_cm = w_qkv^T @ XN (+bias), store bf16 ----------------
// per batch: M=768 (j), N=9216 (s), K=256 (c)
__global__ __launch_bounds__(256)
void qkv_gemm(const float* __restrict__ inp, const float* __restrict__ w_qkv,
              const float* __restrict__ b_qkv, const float* __restrict__ sc_sh,
              __hip_bfloat16* __restrict__ qkv) {
    const int z = blockIdx.z;
    const int j0 = blockIdx.x * 64;
    const int s0 = blockIdx.y * 64;
    const int tid = threadIdx.x;
    const int tx = tid & 15, ty = tid >> 4;

    __shared__ float As[16][64];  // As[kk][jj] = w_qkv[c][j]
    __shared__ float Bs[16][64];  // Bs[kk][ss] = xn[c][s]

    const int lk = tid >> 4;          // 0..15
    const int lm4 = (tid & 15) * 4;   // 0..60

    float acc[4][4] = {};
    for (int k0 = 0; k0 < 256; k0 += 16) {
        float4 a = *reinterpret_cast<const float4*>(w_qkv + (size_t)(k0 + lk) * 768 + j0 + lm4);
        *reinterpret_cast<float4*>(&As[lk][lm4]) = a;
        const int c = k0 + lk;
        const float sc = sc_sh[c], sh = sc_sh[CH + c];
        float4 b = *reinterpret_cast<const float4*>(inp + ((size_t)(z * CH + c)) * SS + s0 + lm4);
        float4 bn;
        bn.x = fmaf(b.x, sc, sh); bn.y = fmaf(b.y, sc, sh);
        bn.z = fmaf(b.z, sc, sh); bn.w = fmaf(b.w, sc, sh);
        *reinterpret_cast<float4*>(&Bs[lk][lm4]) = bn;
        __syncthreads();
        #pragma unroll
        for (int kk = 0; kk < 16; ++kk) {
            float av[4], bv[4];
            #pragma unroll
            for (int i = 0; i < 4; ++i) av[i] = As[kk][ty * 4 + i];
            #pragma unroll
            for (int j = 0; j < 4; ++j) bv[j] = Bs[kk][tx * 4 + j];
            #pragma unroll
            for (int i = 0; i < 4; ++i)
                #pragma unroll
                for (int j = 0; j < 4; ++j)
                    acc[i][j] = fmaf(av[i], bv[j], acc[i][j]);
        }
        __syncthreads();
    }
    #pragma unroll
    for (int i = 0; i < 4; ++i) {
        const int j = j0 + ty * 4 + i;
        const float bias = b_qkv[j];
        __hip_bfloat16* dst = qkv + ((size_t)z * 768 + j) * SS + s0 + tx * 4;
        #pragma unroll
        for (int jj = 0; jj < 4; ++jj) dst[jj] = __float2bfloat16(acc[i][jj] + bias);
    }
}

// ---------------- Stage 3: KV[d][e] = sum_s K[d][s]*V[e][s], split-K atomics ----------------
__global__ __launch_bounds__(256)
void kv_gemm(const __hip_bfloat16* __restrict__ qkv, float* __restrict__ kv) {
    const int z = blockIdx.z;
    const int d0 = (blockIdx.x >> 2) * 64;
    const int e0 = (blockIdx.x & 3) * 64;
    const int s_beg = blockIdx.y * 1152;
    const int tid = threadIdx.x;
    const int tx = tid & 15, ty = tid >> 4;

    __shared__ float Ks[32][65];
    __shared__ float Vs[32][65];

    const __hip_bfloat16* K = qkv + ((size_t)z * 768 + 256) * SS;
    const __hip_bfloat16* V = qkv + ((size_t)z * 768 + 512) * SS;

    const int ld = tid >> 2;         // 0..63
    const int lsb = (tid & 3) * 8;   // 0,8,16,24

    float acc[4][4] = {};
    for (int s0 = s_beg; s0 < s_beg + 1152; s0 += 32) {
        uint4 kp = *reinterpret_cast<const uint4*>(K + (size_t)(d0 + ld) * SS + s0 + lsb);
        uint4 vp = *reinterpret_cast<const uint4*>(V + (size_t)(e0 + ld) * SS + s0 + lsb);
        float kf[8], vf[8];
        bf8_to_f(kp, kf); bf8_to_f(vp, vf);
        #pragma unroll
        for (int u = 0; u < 8; ++u) { Ks[lsb + u][ld] = kf[u]; Vs[lsb + u][ld] = vf[u]; }
        __syncthreads();
        #pragma unroll
        for (int kk = 0; kk < 32; ++kk) {
            float av[4], bv[4];
            #pragma unroll
            for (int i = 0; i < 4; ++i) av[i] = Ks[kk][ty * 4 + i];
            #pragma unroll
            for (int j = 0; j < 4; ++j) bv[j] = Vs[kk][tx * 4 + j];
            #pragma unroll
            for (int i = 0; i < 4; ++i)
                #pragma unroll
                for (int j = 0; j < 4; ++j)
                    acc[i][j] = fmaf(av[i], bv[j], acc[i][j]);
        }
        __syncthreads();
    }
    float* kvz = kv + (size_t)z * 65536;
    #pragma unroll
    for (int i = 0; i < 4; ++i)
        #pragma unroll
        for (int j = 0; j < 4; ++j)
            atomicAdd(&kvz[(size_t)(d0 + ty * 4 + i) * 256 + e0 + tx * 4 + j], acc[i][j]);
}

// ---------------- Stage 4: Acomb[z] = [Wp^T | Wp^T @ KV^T] ----------------
__global__ __launch_bounds__(256)
void build_acomb(const float* __restrict__ w_proj, const float* __restrict__ kv,
                 float* __restrict__ Ac) {
    const int o = blockIdx.x;
    const int z = blockIdx.y;
    const int t = threadIdx.x;
    __shared__ float wcol[256];
    wcol[t] = w_proj[(size_t)t * 256 + o];   // w_proj[e][o]
    __syncthreads();
    const float* kvz = kv + (size_t)z * 65536;
    float acc = 0.f;
    #pragma unroll 4
    for (int e = 0; e < 256; ++e) acc = fmaf(wcol[e], kvz[(size_t)t * 256 + e], acc);
    float* A = Ac + ((size_t)z * 256 + o) * 512;
    A[t] = wcol[t];        // A[o][e] = w_proj[e][o],      e = t
    A[256 + t] = acc;      // A[o][256+d] = sum_e wp[e][o]*kv[d][e], d = t
}

// ---------------- Stage 5: OUT = Acomb @ [V;Q] + b_proj + inp ----------------
// per batch: M=256 (o), N=9216 (s), K=512
__global__ __launch_bounds__(256)
void out_gemm(const float* __restrict__ Ac, const __hip_bfloat16* __restrict__ qkv,
              const float* __restrict__ b_proj, const float* __restrict__ inp,
              float* __restrict__ out) {
    const int z = blockIdx.z;
    const int o0 = blockIdx.x * 64;
    const int s0 = blockIdx.y * 64;
    const int tid = threadIdx.x;
    const int tx = tid & 15, ty = tid >> 4;

    __shared__ float As[16][65];
    __shared__ float Bs[16][64];

    const float* A = Ac + (size_t)z * 256 * 512;
    const __hip_bfloat16* Vb = qkv + ((size_t)z * 768 + 512) * SS;
    const __hip_bfloat16* Qb = qkv + ((size_t)z * 768 + 0) * SS;

    const int lo = tid >> 2;          // 0..63
    const int lkb = (tid & 3) * 4;    // 0,4,8,12
    const int lk = tid >> 4;          // 0..15
    const int ls4 = (tid & 15) * 4;   // 0..60

    float acc[4][4] = {};
    for (int k0 = 0; k0 < 512; k0 += 16) {
        float4 a = *reinterpret_cast<const float4*>(A + (size_t)(o0 + lo) * 512 + k0 + lkb);
        As[lkb + 0][lo] = a.x; As[lkb + 1][lo] = a.y;
        As[lkb + 2][lo] = a.z; As[lkb + 3][lo] = a.w;
        const int kg = k0 + lk;
        const __hip_bfloat16* Brow = (kg < 256) ? (Vb + (size_t)kg * SS)
                                                : (Qb + (size_t)(kg - 256) * SS);
        uint2 bp = *reinterpret_cast<const uint2*>(Brow + s0 + ls4);
        Bs[lk][ls4 + 0] = __uint_as_float(bp.x << 16);
        Bs[lk][ls4 + 1] = __uint_as_float(bp.x & 0xffff0000u);
        Bs[lk][ls4 + 2] = __uint_as_float(bp.y << 16);
        Bs[lk][ls4 + 3] = __uint_as_float(bp.y & 0xffff0000u);
        __syncthreads();
        #pragma unroll
        for (int kk = 0; kk < 16; ++kk) {
            float av[4], bv[4];
            #pragma unroll
            for (int i = 0; i < 4; ++i) av[i] = As[kk][ty * 4 + i];
            #pragma unroll
            for (int j = 0; j < 4; ++j) bv[j] = Bs[kk][tx * 4 + j];
            #pragma unroll
            for (int i = 0; i < 4; ++i)
                #pragma unroll
                for (int j = 0; j < 4; ++j)
                    acc[i][j] = fmaf(av[i], bv[j], acc[i][j]);
        }
        __syncthreads();
    }
    #pragma unroll
    for (int i = 0; i < 4; ++i) {
        const int o = o0 + ty * 4 + i;
        const float bias = b_proj[o];
        const size_t base = ((size_t)z * CH + o) * SS + s0 + tx * 4;
        #pragma unroll
        for (int j = 0; j < 4; ++j)
            out[base + j] = acc[i][j] + bias + inp[base + j];
    }
}

extern "C" void kernel_launch(void* const* d_in, const int* in_sizes, int n_in,
                              void* d_out, int out_size, void* d_ws, size_t ws_size,
                              hipStream_t stream) {
    const float* inp    = (const float*)d_in[0];
    const float* gamma  = (const float*)d_in[1];
    const float* beta   = (const float*)d_in[2];
    const float* w_qkv  = (const float*)d_in[3];
    const float* b_qkv  = (const float*)d_in[4];
    const float* w_proj = (const float*)d_in[5];
    const float* b_proj = (const float*)d_in[6];
    float* out = (float*)d_out;

    char* ws = (char*)d_ws;
    float* sc_sh = (float*)ws;
    float* kv    = (float*)(ws + KV_BYTE_OFF);
    float* Ac    = (float*)(ws + AC_BYTE_OFF);
    __hip_bfloat16* qkv = (__hip_bfloat16*)(ws + QKV_BYTE_OFF);

    hipMemsetAsync(kv, 0, (size_t)NBATCH * 256 * 256 * sizeof(float), stream);

    bn_stats<<<dim3(CH), dim3(256), 0, stream>>>(inp, gamma, beta, sc_sh);
    qkv_gemm<<<dim3(12, 144, NBATCH), dim3(256), 0, stream>>>(inp, w_qkv, b_qkv, sc_sh, qkv);
    kv_gemm<<<dim3(16, 8, NBATCH), dim3(256), 0, stream>>>(qkv, kv);
    build_acomb<<<dim3(256, NBATCH), dim3(256), 0, stream>>>(w_proj, kv, Ac);
    out_gemm<<<dim3(4, 144, NBATCH), dim3(256), 0, stream>>>(Ac, qkv, b_proj, inp, out);
}

// Round 2
// 372.520 us; speedup vs baseline: 2.8647x; 2.8647x over previous
//
#include <hip/hip_runtime.h>
#include <hip/hip_bf16.h>
#include <stdint.h>

#define S 9216
#define C 256
#define J3 768
#define NB 8
#define EPS 1e-5f

typedef __attribute__((ext_vector_type(8))) short bf16x8;
typedef __attribute__((ext_vector_type(4))) float f32x4;
typedef unsigned short u16;
typedef unsigned int u32;

// ---------------- ws layout (bytes) ----------------
// [0, 2048)        : scale[256], shift[256] fp32
// [4096, +384K)    : wT bf16 [768][256]
// [401408, +2MB)   : Acomb bf16 [8][256][512]
// [2506752, +2MB)  : kv fp32 [8][256][256]
// [8388608, +108MB): QKV bf16 [8][9216][768] s-major (j: 0..255 Q, 256..511 K, 512..767 V)
#define WS_WT   4096
#define WS_AC   401408
#define WS_KV   2506752
#define WS_QKV  8388608

__device__ __forceinline__ u16 f2bf(float x) {
    union { float f; u32 u; } v; v.f = x;
    u32 r = v.u + 0x7FFFu + ((v.u >> 16) & 1u);
    return (u16)(r >> 16);
}

// ---------------- Stage 1: BN stats -> scale/shift ----------------
__global__ __launch_bounds__(256)
void bn_stats(const float* __restrict__ inp, const float* __restrict__ gamma,
              const float* __restrict__ beta, float* __restrict__ sc_sh) {
    const int c = blockIdx.x;
    const int tid = threadIdx.x;
    float sum = 0.f, sumsq = 0.f;
    for (int n = 0; n < NB; ++n) {
        const float4* p = (const float4*)(inp + ((size_t)(n * C + c)) * S);
        for (int s = tid; s < S / 4; s += 256) {
            float4 v = p[s];
            sum += v.x + v.y + v.z + v.w;
            sumsq += v.x * v.x + v.y * v.y + v.z * v.z + v.w * v.w;
        }
    }
    #pragma unroll
    for (int off = 32; off > 0; off >>= 1) {
        sum   += __shfl_down(sum, off, 64);
        sumsq += __shfl_down(sumsq, off, 64);
    }
    __shared__ float ssum[4], ssq[4];
    const int wave = tid >> 6, lane = tid & 63;
    if (lane == 0) { ssum[wave] = sum; ssq[wave] = sumsq; }
    __syncthreads();
    if (tid == 0) {
        float s0 = ssum[0] + ssum[1] + ssum[2] + ssum[3];
        float q0 = ssq[0] + ssq[1] + ssq[2] + ssq[3];
        const float invN = 1.0f / (float)(NB * S);
        float m = s0 * invN;
        float var = q0 * invN - m * m;
        float rstd = rsqrtf(var + EPS);
        float sc = gamma[c] * rstd;
        sc_sh[c] = sc;
        sc_sh[C + c] = beta[c] - m * sc;
    }
}

// ---------------- wT[j][c] = bf16(w_qkv[c][j]) ----------------
__global__ __launch_bounds__(256)
void wt_build(const float* __restrict__ w_qkv, u16* __restrict__ wT) {
    const int j = blockIdx.x, c = threadIdx.x;
    wT[(size_t)j * 256 + c] = f2bf(w_qkv[(size_t)c * 768 + j]);
}

// ---------------- Stage 2: QKV[z][s][j] = sum_c XN[s][c]*wT[j][c] + b ----------------
// M=s (tiles of 128), N=j (768 = 6 tiles), K=c (256, BK=32)
__global__ __launch_bounds__(256)
void qkv_gemm(const float* __restrict__ inp, const u16* __restrict__ wT,
              const float* __restrict__ b_qkv, const float* __restrict__ sc_sh,
              u16* __restrict__ qkv) {
    __shared__ u16 Asm[128 * 32];
    __shared__ u16 Bsm[128 * 32];
    const int bid = blockIdx.x;
    const int wid = (bid & 7) * 432 + (bid >> 3);   // XCD swizzle (3456 = 8*432)
    const int jt = wid % 6;
    const int st = (wid / 6) % 72;
    const int z  = wid / 432;

    const int tid = threadIdx.x;
    const int l = tid & 63, w = tid >> 6;
    const int m0 = (w >> 1) * 64, n0 = (w & 1) * 64;
    const int g = l >> 4, r = l & 15;

    const int rowA = tid & 127;            // local row (s for A, j for B)
    const int half = (tid >> 7) * 16;      // which 16-wide half of the 32-wide K slab

    const float* inpz = inp + (size_t)z * C * S + (size_t)st * 128 + rowA;
    const u16* wrow = wT + (size_t)(jt * 128 + rowA) * 256;

    f32x4 acc[4][4];
    #pragma unroll
    for (int i = 0; i < 4; ++i)
        #pragma unroll
        for (int j = 0; j < 4; ++j) acc[i][j] = (f32x4){0.f, 0.f, 0.f, 0.f};

    for (int k0 = 0; k0 < 256; k0 += 32) {
        // stage A: fused BN + transpose: XN^T tile [128 s][32 c]
        {
            u32 pk[8];
            #pragma unroll
            for (int u = 0; u < 8; ++u) {
                const int c = k0 + half + u * 2;
                float x0 = inpz[(size_t)c * S];
                float x1 = inpz[(size_t)(c + 1) * S];
                u16 b0 = f2bf(fmaf(x0, sc_sh[c], sc_sh[C + c]));
                u16 b1 = f2bf(fmaf(x1, sc_sh[c + 1], sc_sh[C + c + 1]));
                pk[u] = (u32)b0 | ((u32)b1 << 16);
            }
            uint4 q0, q1;
            q0.x = pk[0]; q0.y = pk[1]; q0.z = pk[2]; q0.w = pk[3];
            q1.x = pk[4]; q1.y = pk[5]; q1.z = pk[6]; q1.w = pk[7];
            *(uint4*)&Asm[rowA * 32 + half] = q0;
            *(uint4*)&Asm[rowA * 32 + half + 8] = q1;
        }
        // stage B: wT tile [128 j][32 c] (contiguous)
        {
            const uint4* p = (const uint4*)&wrow[k0 + half];
            *(uint4*)&Bsm[rowA * 32 + half] = p[0];
            *(uint4*)&Bsm[rowA * 32 + half + 8] = p[1];
        }
        __syncthreads();
        bf16x8 a[4], b[4];
        #pragma unroll
        for (int i = 0; i < 4; ++i) a[i] = *(const bf16x8*)&Asm[(m0 + i * 16 + r) * 32 + g * 8];
        #pragma unroll
        for (int j = 0; j < 4; ++j) b[j] = *(const bf16x8*)&Bsm[(n0 + j * 16 + r) * 32 + g * 8];
        #pragma unroll
        for (int i = 0; i < 4; ++i)
            #pragma unroll
            for (int j = 0; j < 4; ++j)
                acc[i][j] = __builtin_amdgcn_mfma_f32_16x16x32_bf16(a[i], b[j], acc[i][j], 0, 0, 0);
        __syncthreads();
    }
    // epilogue: D[s][j], col(lane&15)=j, row=(g*4+q)
    #pragma unroll
    for (int i = 0; i < 4; ++i) {
        #pragma unroll
        for (int q = 0; q < 4; ++q) {
            const int s = st * 128 + m0 + i * 16 + g * 4 + q;
            u16* dst = qkv + ((size_t)z * S + s) * 768;
            #pragma unroll
            for (int j = 0; j < 4; ++j) {
                const int jj = jt * 128 + n0 + j * 16 + r;
                dst[jj] = f2bf(acc[i][j][q] + b_qkv[jj]);
            }
        }
    }
}

// ---------------- Stage 3: kv[d][e] = sum_s K[s][d]*V[s][e] ----------------
// in-kernel transposed staging from s-major QKV; split-s=8, fp32 atomics
__global__ __launch_bounds__(256)
void kv_gemm(const u16* __restrict__ qkv, float* __restrict__ kv) {
    __shared__ u16 Asm[128 * 32];
    __shared__ u16 Bsm[128 * 32];
    const int bid = blockIdx.x;
    const int wid = (bid & 7) * 32 + (bid >> 3);   // 256 = 8*32
    const int et = wid & 1;
    const int dt = (wid >> 1) & 1;
    const int sp = (wid >> 2) & 7;
    const int z  = wid >> 5;

    const int tid = threadIdx.x;
    const int l = tid & 63, w = tid >> 6;
    const int m0 = (w >> 1) * 64, n0 = (w & 1) * 64;
    const int g = l >> 4, r = l & 15;

    const int rowL = tid & 127;
    const int isB = tid >> 7;   // 0: stage A (K cols), 1: stage B (V cols)
    const int col = isB ? (512 + et * 128 + rowL) : (256 + dt * 128 + rowL);
    const u16* src = qkv + (size_t)z * S * 768 + col;
    u16* dstL = (isB ? Bsm : Asm) + rowL * 32;

    f32x4 acc[4][4];
    #pragma unroll
    for (int i = 0; i < 4; ++i)
        #pragma unroll
        for (int j = 0; j < 4; ++j) acc[i][j] = (f32x4){0.f, 0.f, 0.f, 0.f};

    const int sbeg = sp * 1152;
    for (int s0 = sbeg; s0 < sbeg + 1152; s0 += 32) {
        u32 pk[16];
        #pragma unroll
        for (int u = 0; u < 16; ++u) {
            u16 a0 = src[(size_t)(s0 + 2 * u) * 768];
            u16 a1 = src[(size_t)(s0 + 2 * u + 1) * 768];
            pk[u] = (u32)a0 | ((u32)a1 << 16);
        }
        #pragma unroll
        for (int u = 0; u < 4; ++u) {
            uint4 q;
            q.x = pk[u * 4]; q.y = pk[u * 4 + 1]; q.z = pk[u * 4 + 2]; q.w = pk[u * 4 + 3];
            *(uint4*)&dstL[u * 8] = q;
        }
        __syncthreads();
        bf16x8 a[4], b[4];
        #pragma unroll
        for (int i = 0; i < 4; ++i) a[i] = *(const bf16x8*)&Asm[(m0 + i * 16 + r) * 32 + g * 8];
        #pragma unroll
        for (int j = 0; j < 4; ++j) b[j] = *(const bf16x8*)&Bsm[(n0 + j * 16 + r) * 32 + g * 8];
        #pragma unroll
        for (int i = 0; i < 4; ++i)
            #pragma unroll
            for (int j = 0; j < 4; ++j)
                acc[i][j] = __builtin_amdgcn_mfma_f32_16x16x32_bf16(a[i], b[j], acc[i][j], 0, 0, 0);
        __syncthreads();
    }
    float* kvz = kv + (size_t)z * 65536;
    #pragma unroll
    for (int i = 0; i < 4; ++i)
        #pragma unroll
        for (int q = 0; q < 4; ++q) {
            const int d = dt * 128 + m0 + i * 16 + g * 4 + q;
            #pragma unroll
            for (int j = 0; j < 4; ++j) {
                const int e = et * 128 + n0 + j * 16 + r;
                atomicAdd(&kvz[(size_t)d * 256 + e], acc[i][j][q]);
            }
        }
}

// ---------------- Stage 4: Acomb[z][o][k] bf16 = [Wp^T | Wp^T @ KV^T] ----------------
__global__ __launch_bounds__(256)
void build_acomb(const float* __restrict__ w_proj, const float* __restrict__ kv,
                 u16* __restrict__ Ab) {
    const int o = blockIdx.x, z = blockIdx.y, t = threadIdx.x;
    __shared__ float wcol[256];
    wcol[t] = w_proj[(size_t)t * 256 + o];
    __syncthreads();
    const float* kvz = kv + (size_t)z * 65536;
    float acc = 0.f;
    #pragma unroll 4
    for (int e = 0; e < 256; ++e) acc = fmaf(wcol[e], kvz[(size_t)t * 256 + e], acc);
    u16* A = Ab + ((size_t)z * 256 + o) * 512;
    A[t] = f2bf(wcol[t]);        // k<256: w_proj[e][o]
    A[256 + t] = f2bf(acc);      // k>=256: (Wp^T KV^T)[o][d]
}

// ---------------- Stage 5: OUT[o][s] = Acomb[o][:] . B[s][:] + b + inp ----------------
// B rows come directly from QKV_sm rows: k<256 -> V (j=512+k), k>=256 -> Q (j=k-256)
__global__ __launch_bounds__(256)
void out_gemm(const u16* __restrict__ Ab, const u16* __restrict__ qkv,
              const float* __restrict__ b_proj, const float* __restrict__ inp,
              float* __restrict__ out) {
    __shared__ u16 Asm[128 * 32];
    __shared__ u16 Bsm[128 * 32];
    const int bid = blockIdx.x;
    const int wid = (bid & 7) * 144 + (bid >> 3);   // 1152 = 8*144
    const int ot = wid & 1;
    const int st = (wid >> 1) % 72;
    const int z  = wid / 144;

    const int tid = threadIdx.x;
    const int l = tid & 63, w = tid >> 6;
    const int m0 = (w >> 1) * 64, n0 = (w & 1) * 64;
    const int g = l >> 4, r = l & 15;

    const int rowL = tid & 127;
    const int half = (tid >> 7) * 16;

    const u16* arow = Ab + (size_t)(z * 256 + ot * 128 + rowL) * 512;
    const u16* brow = qkv + ((size_t)z * S + st * 128 + rowL) * 768;

    f32x4 acc[4][4];
    #pragma unroll
    for (int i = 0; i < 4; ++i)
        #pragma unroll
        for (int j = 0; j < 4; ++j) acc[i][j] = (f32x4){0.f, 0.f, 0.f, 0.f};

    for (int k0 = 0; k0 < 512; k0 += 32) {
        {
            const uint4* p = (const uint4*)&arow[k0 + half];
            *(uint4*)&Asm[rowL * 32 + half] = p[0];
            *(uint4*)&Asm[rowL * 32 + half + 8] = p[1];
        }
        {
            const int off = (k0 < 256) ? (512 + k0) : (k0 - 256);
            const uint4* p = (const uint4*)&brow[off + half];
            *(uint4*)&Bsm[rowL * 32 + half] = p[0];
            *(uint4*)&Bsm[rowL * 32 + half + 8] = p[1];
        }
        __syncthreads();
        bf16x8 a[4], b[4];
        #pragma unroll
        for (int i = 0; i < 4; ++i) a[i] = *(const bf16x8*)&Asm[(m0 + i * 16 + r) * 32 + g * 8];
        #pragma unroll
        for (int j = 0; j < 4; ++j) b[j] = *(const bf16x8*)&Bsm[(n0 + j * 16 + r) * 32 + g * 8];
        #pragma unroll
        for (int i = 0; i < 4; ++i)
            #pragma unroll
            for (int j = 0; j < 4; ++j)
                acc[i][j] = __builtin_amdgcn_mfma_f32_16x16x32_bf16(a[i], b[j], acc[i][j], 0, 0, 0);
        __syncthreads();
    }
    // epilogue: D[o][s], col=s (coalesced fp32 stores), + bias + residual
    #pragma unroll
    for (int i = 0; i < 4; ++i) {
        #pragma unroll
        for (int q = 0; q < 4; ++q) {
            const int o = ot * 128 + m0 + i * 16 + g * 4 + q;
            const float bias = b_proj[o];
            const size_t base = ((size_t)z * C + o) * S + st * 128;
            #pragma unroll
            for (int j = 0; j < 4; ++j) {
                const int sl = n0 + j * 16 + r;
                out[base + sl] = acc[i][j][q] + bias + inp[base + sl];
            }
        }
    }
}

extern "C" void kernel_launch(void* const* d_in, const int* in_sizes, int n_in,
                              void* d_out, int out_size, void* d_ws, size_t ws_size,
                              hipStream_t stream) {
    const float* inp    = (const float*)d_in[0];
    const float* gamma  = (const float*)d_in[1];
    const float* beta   = (const float*)d_in[2];
    const float* w_qkv  = (const float*)d_in[3];
    const float* b_qkv  = (const float*)d_in[4];
    const float* w_proj = (const float*)d_in[5];
    const float* b_proj = (const float*)d_in[6];
    float* out = (float*)d_out;

    char* ws = (char*)d_ws;
    float* sc_sh = (float*)ws;
    u16*   wT    = (u16*)(ws + WS_WT);
    u16*   Ab    = (u16*)(ws + WS_AC);
    float* kv    = (float*)(ws + WS_KV);
    u16*   qkv   = (u16*)(ws + WS_QKV);

    hipMemsetAsync(kv, 0, (size_t)NB * 256 * 256 * sizeof(float), stream);

    bn_stats<<<dim3(C), dim3(256), 0, stream>>>(inp, gamma, beta, sc_sh);
    wt_build<<<dim3(J3), dim3(256), 0, stream>>>(w_qkv, wT);
    qkv_gemm<<<dim3(3456), dim3(256), 0, stream>>>(inp, wT, b_qkv, sc_sh, qkv);
    kv_gemm<<<dim3(256), dim3(256), 0, stream>>>(qkv, kv);
    build_acomb<<<dim3(256, NB), dim3(256), 0, stream>>>(w_proj, kv, Ab);
    out_gemm<<<dim3(1152), dim3(256), 0, stream>>>(Ab, qkv, b_proj, inp, out);
}

// Round 3
// 258.343 us; speedup vs baseline: 4.1307x; 1.4420x over previous
//
#include <hip/hip_runtime.h>
#include <hip/hip_bf16.h>
#include <stdint.h>

#define S 9216
#define C 256
#define NB 8
#define EPS 1e-5f

typedef __attribute__((ext_vector_type(8))) short bf16x8;
typedef __attribute__((ext_vector_type(4))) float f32x4;
typedef unsigned short u16;
typedef unsigned int u32;

// ---------------- ws layout (bytes) ----------------
// [0, 2048)           : scale[256], shift[256] fp32
// [4096, +256K)       : wT512 bf16 [512][256]   (rows 0..255 = K-proj cols, 256..511 = V-proj cols)
// [266240, +128K)     : wpT bf16 [256][256]
// [397312, +1MB)      : Ac2 bf16 [8][256][256]
// [1445888, +1MB)     : M bf16 [8][256][256]
// [2494464, +8K)      : constz fp32 [8][256]
// [2506752, +2MB)     : kv fp32 [8][256][256]
// [8388608, +72MB)    : KV bf16 [8][9216][512]  (cols 0..255 = K, 256..511 = V)
#define WS_WT   4096
#define WS_WPT  266240
#define WS_AC2  397312
#define WS_M    1445888
#define WS_CZ   2494464
#define WS_KV   2506752
#define WS_QKV  8388608

__device__ __forceinline__ u16 f2bf(float x) {
    union { float f; u32 u; } v; v.f = x;
    u32 r = v.u + 0x7FFFu + ((v.u >> 16) & 1u);
    return (u16)(r >> 16);
}
__device__ __forceinline__ float bf2f(u16 b) { return __uint_as_float((u32)b << 16); }

// stage 16 contiguous fp32 -> 16 bf16 into LDS
__device__ __forceinline__ void stage16f(const float* __restrict__ src, u16* __restrict__ dst) {
    const float4* p = (const float4*)src;
    float4 f0 = p[0], f1 = p[1], f2 = p[2], f3 = p[3];
    uint4 q0, q1;
    q0.x = (u32)f2bf(f0.x) | ((u32)f2bf(f0.y) << 16);
    q0.y = (u32)f2bf(f0.z) | ((u32)f2bf(f0.w) << 16);
    q0.z = (u32)f2bf(f1.x) | ((u32)f2bf(f1.y) << 16);
    q0.w = (u32)f2bf(f1.z) | ((u32)f2bf(f1.w) << 16);
    q1.x = (u32)f2bf(f2.x) | ((u32)f2bf(f2.y) << 16);
    q1.y = (u32)f2bf(f2.z) | ((u32)f2bf(f2.w) << 16);
    q1.z = (u32)f2bf(f3.x) | ((u32)f2bf(f3.y) << 16);
    q1.w = (u32)f2bf(f3.z) | ((u32)f2bf(f3.w) << 16);
    *(uint4*)dst = q0;
    *(uint4*)(dst + 8) = q1;
}

// ---------------- Stage 1: BN stats -> scale/shift ----------------
__global__ __launch_bounds__(256)
void bn_stats(const float* __restrict__ inp, const float* __restrict__ gamma,
              const float* __restrict__ beta, float* __restrict__ sc_sh) {
    const int c = blockIdx.x;
    const int tid = threadIdx.x;
    float sum = 0.f, sumsq = 0.f;
    for (int n = 0; n < NB; ++n) {
        const float4* p = (const float4*)(inp + ((size_t)(n * C + c)) * S);
        for (int s = tid; s < S / 4; s += 256) {
            float4 v = p[s];
            sum += v.x + v.y + v.z + v.w;
            sumsq += v.x * v.x + v.y * v.y + v.z * v.z + v.w * v.w;
        }
    }
    #pragma unroll
    for (int off = 32; off > 0; off >>= 1) {
        sum   += __shfl_down(sum, off, 64);
        sumsq += __shfl_down(sumsq, off, 64);
    }
    __shared__ float ssum[4], ssq[4];
    const int wave = tid >> 6, lane = tid & 63;
    if (lane == 0) { ssum[wave] = sum; ssq[wave] = sumsq; }
    __syncthreads();
    if (tid == 0) {
        float s0 = ssum[0] + ssum[1] + ssum[2] + ssum[3];
        float q0 = ssq[0] + ssq[1] + ssq[2] + ssq[3];
        const float invN = 1.0f / (float)(NB * S);
        float m = s0 * invN;
        float var = q0 * invN - m * m;
        float rstd = rsqrtf(var + EPS);
        float sc = gamma[c] * rstd;
        sc_sh[c] = sc;
        sc_sh[C + c] = beta[c] - m * sc;
    }
}

// ---------------- weight transposes: wT512[jj][c]=w_qkv[c][256+jj], wpT[o][e]=w_proj[e][o] ----------------
__global__ __launch_bounds__(256)
void wt_build(const float* __restrict__ w_qkv, const float* __restrict__ w_proj,
              u16* __restrict__ wT512, u16* __restrict__ wpT) {
    const int r0 = blockIdx.x, c = threadIdx.x;
    if (r0 < 512) {
        wT512[(size_t)r0 * 256 + c] = f2bf(w_qkv[(size_t)c * 768 + 256 + r0]);
    } else {
        const int o = r0 - 512;
        wpT[(size_t)o * 256 + c] = f2bf(w_proj[(size_t)c * 256 + o]);
    }
}

// ---------------- Stage 2: KV[z][s][jj] = sum_c XN[s][c]*wT512[jj][c] + b, jj in [0,512) ----------------
__global__ __launch_bounds__(256)
void kvproj_gemm(const float* __restrict__ inp, const u16* __restrict__ wT512,
                 const float* __restrict__ b_qkv, const float* __restrict__ sc_sh,
                 u16* __restrict__ kvbuf) {
    __shared__ u16 Asm[128 * 32];
    __shared__ u16 Bsm[128 * 32];
    const int bid = blockIdx.x;
    const int wid = (bid & 7) * 288 + (bid >> 3);   // 2304 = 8*288
    const int jt = wid & 3;
    const int st = (wid >> 2) % 72;
    const int z  = wid / 288;

    const int tid = threadIdx.x;
    const int l = tid & 63, w = tid >> 6;
    const int m0 = (w >> 1) * 64, n0 = (w & 1) * 64;
    const int g = l >> 4, r = l & 15;

    const int rowA = tid & 127;
    const int half = (tid >> 7) * 16;

    const float* inpz = inp + (size_t)z * C * S + (size_t)st * 128 + rowA;
    const u16* wrow = wT512 + (size_t)(jt * 128 + rowA) * 256;

    f32x4 acc[4][4];
    #pragma unroll
    for (int i = 0; i < 4; ++i)
        #pragma unroll
        for (int j = 0; j < 4; ++j) acc[i][j] = (f32x4){0.f, 0.f, 0.f, 0.f};

    for (int k0 = 0; k0 < 256; k0 += 32) {
        {   // A: fused BN + transpose: XN^T tile [128 s][32 c]
            u32 pk[8];
            #pragma unroll
            for (int u = 0; u < 8; ++u) {
                const int c = k0 + half + u * 2;
                float x0 = inpz[(size_t)c * S];
                float x1 = inpz[(size_t)(c + 1) * S];
                u16 b0 = f2bf(fmaf(x0, sc_sh[c], sc_sh[C + c]));
                u16 b1 = f2bf(fmaf(x1, sc_sh[c + 1], sc_sh[C + c + 1]));
                pk[u] = (u32)b0 | ((u32)b1 << 16);
            }
            uint4 q0, q1;
            q0.x = pk[0]; q0.y = pk[1]; q0.z = pk[2]; q0.w = pk[3];
            q1.x = pk[4]; q1.y = pk[5]; q1.z = pk[6]; q1.w = pk[7];
            *(uint4*)&Asm[rowA * 32 + half] = q0;
            *(uint4*)&Asm[rowA * 32 + half + 8] = q1;
        }
        {   // B: wT512 tile (contiguous bf16)
            const uint4* p = (const uint4*)&wrow[k0 + half];
            *(uint4*)&Bsm[rowA * 32 + half] = p[0];
            *(uint4*)&Bsm[rowA * 32 + half + 8] = p[1];
        }
        __syncthreads();
        bf16x8 a[4], b[4];
        #pragma unroll
        for (int i = 0; i < 4; ++i) a[i] = *(const bf16x8*)&Asm[(m0 + i * 16 + r) * 32 + g * 8];
        #pragma unroll
        for (int j = 0; j < 4; ++j) b[j] = *(const bf16x8*)&Bsm[(n0 + j * 16 + r) * 32 + g * 8];
        #pragma unroll
        for (int i = 0; i < 4; ++i)
            #pragma unroll
            for (int j = 0; j < 4; ++j)
                acc[i][j] = __builtin_amdgcn_mfma_f32_16x16x32_bf16(a[i], b[j], acc[i][j], 0, 0, 0);
        __syncthreads();
    }
    #pragma unroll
    for (int i = 0; i < 4; ++i) {
        #pragma unroll
        for (int q = 0; q < 4; ++q) {
            const int s = st * 128 + m0 + i * 16 + g * 4 + q;
            u16* dst = kvbuf + ((size_t)z * S + s) * 512;
            #pragma unroll
            for (int j = 0; j < 4; ++j) {
                const int jj = jt * 128 + n0 + j * 16 + r;
                dst[jj] = f2bf(acc[i][j][q] + b_qkv[256 + jj]);
            }
        }
    }
}

// ---------------- Stage 3: kv[d][e] = sum_s K[s][d]*V[s][e] (split-s=8, atomics) ----------------
__global__ __launch_bounds__(256)
void kv_gemm(const u16* __restrict__ kvbuf, float* __restrict__ kv) {
    __shared__ u16 Asm[128 * 32];
    __shared__ u16 Bsm[128 * 32];
    const int bid = blockIdx.x;
    const int wid = (bid & 7) * 32 + (bid >> 3);   // 256 = 8*32
    const int et = wid & 1;
    const int dt = (wid >> 1) & 1;
    const int sp = (wid >> 2) & 7;
    const int z  = wid >> 5;

    const int tid = threadIdx.x;
    const int l = tid & 63, w = tid >> 6;
    const int m0 = (w >> 1) * 64, n0 = (w & 1) * 64;
    const int g = l >> 4, r = l & 15;

    const int rowL = tid & 127;
    const int isB = tid >> 7;
    const int col = isB ? (256 + et * 128 + rowL) : (dt * 128 + rowL);
    const u16* src = kvbuf + (size_t)z * S * 512 + col;
    u16* dstL = (isB ? Bsm : Asm) + rowL * 32;

    f32x4 acc[4][4];
    #pragma unroll
    for (int i = 0; i < 4; ++i)
        #pragma unroll
        for (int j = 0; j < 4; ++j) acc[i][j] = (f32x4){0.f, 0.f, 0.f, 0.f};

    const int sbeg = sp * 1152;
    for (int s0 = sbeg; s0 < sbeg + 1152; s0 += 32) {
        u32 pk[16];
        #pragma unroll
        for (int u = 0; u < 16; ++u) {
            u16 a0 = src[(size_t)(s0 + 2 * u) * 512];
            u16 a1 = src[(size_t)(s0 + 2 * u + 1) * 512];
            pk[u] = (u32)a0 | ((u32)a1 << 16);
        }
        #pragma unroll
        for (int u = 0; u < 4; ++u) {
            uint4 q;
            q.x = pk[u * 4]; q.y = pk[u * 4 + 1]; q.z = pk[u * 4 + 2]; q.w = pk[u * 4 + 3];
            *(uint4*)&dstL[u * 8] = q;
        }
        __syncthreads();
        bf16x8 a[4], b[4];
        #pragma unroll
        for (int i = 0; i < 4; ++i) a[i] = *(const bf16x8*)&Asm[(m0 + i * 16 + r) * 32 + g * 8];
        #pragma unroll
        for (int j = 0; j < 4; ++j) b[j] = *(const bf16x8*)&Bsm[(n0 + j * 16 + r) * 32 + g * 8];
        #pragma unroll
        for (int i = 0; i < 4; ++i)
            #pragma unroll
            for (int j = 0; j < 4; ++j)
                acc[i][j] = __builtin_amdgcn_mfma_f32_16x16x32_bf16(a[i], b[j], acc[i][j], 0, 0, 0);
        __syncthreads();
    }
    float* kvz = kv + (size_t)z * 65536;
    #pragma unroll
    for (int i = 0; i < 4; ++i)
        #pragma unroll
        for (int q = 0; q < 4; ++q) {
            const int d = dt * 128 + m0 + i * 16 + g * 4 + q;
            #pragma unroll
            for (int j = 0; j < 4; ++j) {
                const int e = et * 128 + n0 + j * 16 + r;
                atomicAdd(&kvz[(size_t)d * 256 + e], acc[i][j][q]);
            }
        }
}

// ---------------- Stage 4a: Ac2[z][o][d] = sum_e wpT[o][e] * kv[z][d][e] ----------------
// grid 32: z = bid>>2, ot = (bid>>1)&1, dt = bid&1
__global__ __launch_bounds__(256)
void ac2_gemm(const u16* __restrict__ wpT, const float* __restrict__ kv,
              u16* __restrict__ Ac2) {
    __shared__ u16 Asm[128 * 32];
    __shared__ u16 Bsm[128 * 32];
    const int bid = blockIdx.x;
    const int z = bid >> 2, ot = (bid >> 1) & 1, dt = bid & 1;

    const int tid = threadIdx.x;
    const int l = tid & 63, w = tid >> 6;
    const int m0 = (w >> 1) * 64, n0 = (w & 1) * 64;
    const int g = l >> 4, r = l & 15;

    const int rowL = tid & 127;
    const int half = (tid >> 7) * 16;

    const u16* arow = wpT + (size_t)(ot * 128 + rowL) * 256;
    const float* brow = kv + (size_t)z * 65536 + (size_t)(dt * 128 + rowL) * 256;

    f32x4 acc[4][4];
    #pragma unroll
    for (int i = 0; i < 4; ++i)
        #pragma unroll
        for (int j = 0; j < 4; ++j) acc[i][j] = (f32x4){0.f, 0.f, 0.f, 0.f};

    for (int k0 = 0; k0 < 256; k0 += 32) {
        {
            const uint4* p = (const uint4*)&arow[k0 + half];
            *(uint4*)&Asm[rowL * 32 + half] = p[0];
            *(uint4*)&Asm[rowL * 32 + half + 8] = p[1];
        }
        stage16f(brow + k0 + half, &Bsm[rowL * 32 + half]);
        __syncthreads();
        bf16x8 a[4], b[4];
        #pragma unroll
        for (int i = 0; i < 4; ++i) a[i] = *(const bf16x8*)&Asm[(m0 + i * 16 + r) * 32 + g * 8];
        #pragma unroll
        for (int j = 0; j < 4; ++j) b[j] = *(const bf16x8*)&Bsm[(n0 + j * 16 + r) * 32 + g * 8];
        #pragma unroll
        for (int i = 0; i < 4; ++i)
            #pragma unroll
            for (int j = 0; j < 4; ++j)
                acc[i][j] = __builtin_amdgcn_mfma_f32_16x16x32_bf16(a[i], b[j], acc[i][j], 0, 0, 0);
        __syncthreads();
    }
    u16* Az = Ac2 + (size_t)z * 65536;
    #pragma unroll
    for (int i = 0; i < 4; ++i)
        #pragma unroll
        for (int q = 0; q < 4; ++q) {
            const int o = ot * 128 + m0 + i * 16 + g * 4 + q;
            #pragma unroll
            for (int j = 0; j < 4; ++j) {
                const int d = dt * 128 + n0 + j * 16 + r;
                Az[(size_t)o * 256 + d] = f2bf(acc[i][j][q]);
            }
        }
}

// ---------------- Stage 4b: M[z][o][c] = sum_e wpT[o][e]*wv[c][e] + sum_d Ac2[o][d]*wq[c][d] ----------------
// K=512 concat: k<256 -> A=wpT[o][k], B=w_qkv[c][512+k]; k>=256 -> A=Ac2[o][k-256], B=w_qkv[c][k-256]
__global__ __launch_bounds__(256)
void m_gemm(const u16* __restrict__ wpT, const u16* __restrict__ Ac2,
            const float* __restrict__ w_qkv, u16* __restrict__ M) {
    __shared__ u16 Asm[128 * 32];
    __shared__ u16 Bsm[128 * 32];
    const int bid = blockIdx.x;
    const int z = bid >> 2, ot = (bid >> 1) & 1, ct = bid & 1;

    const int tid = threadIdx.x;
    const int l = tid & 63, w = tid >> 6;
    const int m0 = (w >> 1) * 64, n0 = (w & 1) * 64;
    const int g = l >> 4, r = l & 15;

    const int rowL = tid & 127;
    const int half = (tid >> 7) * 16;

    const u16* wprow = wpT + (size_t)(ot * 128 + rowL) * 256;
    const u16* acrow = Ac2 + (size_t)z * 65536 + (size_t)(ot * 128 + rowL) * 256;
    const float* qrow = w_qkv + (size_t)(ct * 128 + rowL) * 768;

    f32x4 acc[4][4];
    #pragma unroll
    for (int i = 0; i < 4; ++i)
        #pragma unroll
        for (int j = 0; j < 4; ++j) acc[i][j] = (f32x4){0.f, 0.f, 0.f, 0.f};

    for (int k0 = 0; k0 < 512; k0 += 32) {
        {
            const u16* arow = (k0 < 256) ? (wprow + k0) : (acrow + (k0 - 256));
            const uint4* p = (const uint4*)&arow[half];
            *(uint4*)&Asm[rowL * 32 + half] = p[0];
            *(uint4*)&Asm[rowL * 32 + half + 8] = p[1];
        }
        {
            const int off = (k0 < 256) ? (512 + k0) : (k0 - 256);
            stage16f(qrow + off + half, &Bsm[rowL * 32 + half]);
        }
        __syncthreads();
        bf16x8 a[4], b[4];
        #pragma unroll
        for (int i = 0; i < 4; ++i) a[i] = *(const bf16x8*)&Asm[(m0 + i * 16 + r) * 32 + g * 8];
        #pragma unroll
        for (int j = 0; j < 4; ++j) b[j] = *(const bf16x8*)&Bsm[(n0 + j * 16 + r) * 32 + g * 8];
        #pragma unroll
        for (int i = 0; i < 4; ++i)
            #pragma unroll
            for (int j = 0; j < 4; ++j)
                acc[i][j] = __builtin_amdgcn_mfma_f32_16x16x32_bf16(a[i], b[j], acc[i][j], 0, 0, 0);
        __syncthreads();
    }
    u16* Mz = M + (size_t)z * 65536;
    #pragma unroll
    for (int i = 0; i < 4; ++i)
        #pragma unroll
        for (int q = 0; q < 4; ++q) {
            const int o = ot * 128 + m0 + i * 16 + g * 4 + q;
            #pragma unroll
            for (int j = 0; j < 4; ++j) {
                const int c = ct * 128 + n0 + j * 16 + r;
                Mz[(size_t)o * 256 + c] = f2bf(acc[i][j][q]);
            }
        }
}

// ---------------- Stage 4c: constz[z][o] = b_proj[o] + sum_e wpT[o][e]*bv[e] + sum_d Ac2[o][d]*bq[d] ----------------
__global__ __launch_bounds__(256)
void cvec(const u16* __restrict__ wpT, const u16* __restrict__ Ac2,
          const float* __restrict__ b_qkv, const float* __restrict__ b_proj,
          float* __restrict__ constz) {
    const int z = blockIdx.x, o = threadIdx.x;
    const u16* wprow = wpT + (size_t)o * 256;
    const u16* acrow = Ac2 + (size_t)z * 65536 + (size_t)o * 256;
    float acc = b_proj[o];
    #pragma unroll 4
    for (int e = 0; e < 256; ++e) acc = fmaf(bf2f(wprow[e]), b_qkv[512 + e], acc);
    #pragma unroll 4
    for (int d = 0; d < 256; ++d) acc = fmaf(bf2f(acrow[d]), b_qkv[d], acc);
    constz[z * 256 + o] = acc;
}

// ---------------- Stage 5: OUT[o][s] = M[o][:] . xn[:][s] + constz[o] + inp[o][s] ----------------
__global__ __launch_bounds__(256)
void out_gemm(const u16* __restrict__ M, const float* __restrict__ inp,
              const float* __restrict__ sc_sh, const float* __restrict__ constz,
              float* __restrict__ out) {
    __shared__ u16 Asm[128 * 32];
    __shared__ u16 Bsm[128 * 32];
    const int bid = blockIdx.x;
    const int wid = (bid & 7) * 144 + (bid >> 3);   // 1152 = 8*144
    const int ot = wid & 1;
    const int st = (wid >> 1) % 72;
    const int z  = wid / 144;

    const int tid = threadIdx.x;
    const int l = tid & 63, w = tid >> 6;
    const int m0 = (w >> 1) * 64, n0 = (w & 1) * 64;
    const int g = l >> 4, r = l & 15;

    const int rowL = tid & 127;
    const int half = (tid >> 7) * 16;

    const u16* arow = M + (size_t)z * 65536 + (size_t)(ot * 128 + rowL) * 256;
    const float* inpz = inp + (size_t)z * C * S + (size_t)st * 128 + rowL;

    f32x4 acc[4][4];
    #pragma unroll
    for (int i = 0; i < 4; ++i)
        #pragma unroll
        for (int j = 0; j < 4; ++j) acc[i][j] = (f32x4){0.f, 0.f, 0.f, 0.f};

    for (int k0 = 0; k0 < 256; k0 += 32) {
        {   // A: M rows (contiguous bf16)
            const uint4* p = (const uint4*)&arow[k0 + half];
            *(uint4*)&Asm[rowL * 32 + half] = p[0];
            *(uint4*)&Asm[rowL * 32 + half + 8] = p[1];
        }
        {   // B: fused BN + transpose: XN^T tile [128 s][32 c]
            u32 pk[8];
            #pragma unroll
            for (int u = 0; u < 8; ++u) {
                const int c = k0 + half + u * 2;
                float x0 = inpz[(size_t)c * S];
                float x1 = inpz[(size_t)(c + 1) * S];
                u16 b0 = f2bf(fmaf(x0, sc_sh[c], sc_sh[C + c]));
                u16 b1 = f2bf(fmaf(x1, sc_sh[c + 1], sc_sh[C + c + 1]));
                pk[u] = (u32)b0 | ((u32)b1 << 16);
            }
            uint4 q0, q1;
            q0.x = pk[0]; q0.y = pk[1]; q0.z = pk[2]; q0.w = pk[3];
            q1.x = pk[4]; q1.y = pk[5]; q1.z = pk[6]; q1.w = pk[7];
            *(uint4*)&Bsm[rowL * 32 + half] = q0;
            *(uint4*)&Bsm[rowL * 32 + half + 8] = q1;
        }
        __syncthreads();
        bf16x8 a[4], b[4];
        #pragma unroll
        for (int i = 0; i < 4; ++i) a[i] = *(const bf16x8*)&Asm[(m0 + i * 16 + r) * 32 + g * 8];
        #pragma unroll
        for (int j = 0; j < 4; ++j) b[j] = *(const bf16x8*)&Bsm[(n0 + j * 16 + r) * 32 + g * 8];
        #pragma unroll
        for (int i = 0; i < 4; ++i)
            #pragma unroll
            for (int j = 0; j < 4; ++j)
                acc[i][j] = __builtin_amdgcn_mfma_f32_16x16x32_bf16(a[i], b[j], acc[i][j], 0, 0, 0);
        __syncthreads();
    }
    #pragma unroll
    for (int i = 0; i < 4; ++i) {
        #pragma unroll
        for (int q = 0; q < 4; ++q) {
            const int o = ot * 128 + m0 + i * 16 + g * 4 + q;
            const float cz = constz[z * 256 + o];
            const size_t base = ((size_t)z * C + o) * S + st * 128;
            #pragma unroll
            for (int j = 0; j < 4; ++j) {
                const int sl = n0 + j * 16 + r;
                out[base + sl] = acc[i][j][q] + cz + inp[base + sl];
            }
        }
    }
}

extern "C" void kernel_launch(void* const* d_in, const int* in_sizes, int n_in,
                              void* d_out, int out_size, void* d_ws, size_t ws_size,
                              hipStream_t stream) {
    const float* inp    = (const float*)d_in[0];
    const float* gamma  = (const float*)d_in[1];
    const float* beta   = (const float*)d_in[2];
    const float* w_qkv  = (const float*)d_in[3];
    const float* b_qkv  = (const float*)d_in[4];
    const float* w_proj = (const float*)d_in[5];
    const float* b_proj = (const float*)d_in[6];
    float* out = (float*)d_out;

    char* ws = (char*)d_ws;
    float* sc_sh = (float*)ws;
    u16*   wT512 = (u16*)(ws + WS_WT);
    u16*   wpT   = (u16*)(ws + WS_WPT);
    u16*   Ac2   = (u16*)(ws + WS_AC2);
    u16*   Mm    = (u16*)(ws + WS_M);
    float* cz    = (float*)(ws + WS_CZ);
    float* kv    = (float*)(ws + WS_KV);
    u16*   kvbuf = (u16*)(ws + WS_QKV);

    hipMemsetAsync(kv, 0, (size_t)NB * 256 * 256 * sizeof(float), stream);

    bn_stats<<<dim3(C), dim3(256), 0, stream>>>(inp, gamma, beta, sc_sh);
    wt_build<<<dim3(768), dim3(256), 0, stream>>>(w_qkv, w_proj, wT512, wpT);
    kvproj_gemm<<<dim3(2304), dim3(256), 0, stream>>>(inp, wT512, b_qkv, sc_sh, kvbuf);
    kv_gemm<<<dim3(256), dim3(256), 0, stream>>>(kvbuf, kv);
    ac2_gemm<<<dim3(32), dim3(256), 0, stream>>>(wpT, kv, Ac2);
    m_gemm<<<dim3(32), dim3(256), 0, stream>>>(wpT, Ac2, w_qkv, Mm);
    cvec<<<dim3(NB), dim3(256), 0, stream>>>(wpT, Ac2, b_qkv, b_proj, cz);
    out_gemm<<<dim3(1152), dim3(256), 0, stream>>>(Mm, inp, sc_sh, cz, out);
}

// Round 4
// 250.665 us; speedup vs baseline: 4.2573x; 1.0306x over previous
//
#include <hip/hip_runtime.h>
#include <hip/hip_bf16.h>
#include <stdint.h>

#define S 9216
#define C 256
#define NB 8
#define EPS 1e-5f
#define LDST 40   // LDS row stride in u16 (80B = 20 words): conflict-free for b128 r/w

typedef __attribute__((ext_vector_type(8))) short bf16x8;
typedef __attribute__((ext_vector_type(4))) float f32x4;
typedef unsigned short u16;
typedef unsigned int u32;

// ---------------- ws layout (bytes) ----------------
#define WS_WT   4096       // wT512 bf16 [512][256]
#define WS_WPT  266240     // wpT bf16 [256][256]
#define WS_AC2  397312     // Ac2 bf16 [8][256][256]
#define WS_M    1445888    // M bf16 [8][256][256]
#define WS_CZ   2494464    // constz fp32 [8][256]
#define WS_KV   2506752    // kv fp32 [8][256][256]
#define WS_QKV  8388608    // KV bf16 [8][9216][512]

__device__ __forceinline__ u16 f2bf(float x) {
    union { float f; u32 u; } v; v.f = x;
    u32 r = v.u + 0x7FFFu + ((v.u >> 16) & 1u);
    return (u16)(r >> 16);
}
__device__ __forceinline__ float bf2f(u16 b) { return __uint_as_float((u32)b << 16); }

__device__ __forceinline__ void stage16f(const float* __restrict__ src, u16* __restrict__ dst) {
    const float4* p = (const float4*)src;
    float4 f0 = p[0], f1 = p[1], f2 = p[2], f3 = p[3];
    uint4 q0, q1;
    q0.x = (u32)f2bf(f0.x) | ((u32)f2bf(f0.y) << 16);
    q0.y = (u32)f2bf(f0.z) | ((u32)f2bf(f0.w) << 16);
    q0.z = (u32)f2bf(f1.x) | ((u32)f2bf(f1.y) << 16);
    q0.w = (u32)f2bf(f1.z) | ((u32)f2bf(f1.w) << 16);
    q1.x = (u32)f2bf(f2.x) | ((u32)f2bf(f2.y) << 16);
    q1.y = (u32)f2bf(f2.z) | ((u32)f2bf(f2.w) << 16);
    q1.z = (u32)f2bf(f3.x) | ((u32)f2bf(f3.y) << 16);
    q1.w = (u32)f2bf(f3.z) | ((u32)f2bf(f3.w) << 16);
    *(uint4*)dst = q0;
    *(uint4*)(dst + 8) = q1;
}

// ---------------- Stage 1: BN stats -> scale/shift ----------------
__global__ __launch_bounds__(256)
void bn_stats(const float* __restrict__ inp, const float* __restrict__ gamma,
              const float* __restrict__ beta, float* __restrict__ sc_sh) {
    const int c = blockIdx.x;
    const int tid = threadIdx.x;
    float sum = 0.f, sumsq = 0.f;
    for (int n = 0; n < NB; ++n) {
        const float4* p = (const float4*)(inp + ((size_t)(n * C + c)) * S);
        for (int s = tid; s < S / 4; s += 256) {
            float4 v = p[s];
            sum += v.x + v.y + v.z + v.w;
            sumsq += v.x * v.x + v.y * v.y + v.z * v.z + v.w * v.w;
        }
    }
    #pragma unroll
    for (int off = 32; off > 0; off >>= 1) {
        sum   += __shfl_down(sum, off, 64);
        sumsq += __shfl_down(sumsq, off, 64);
    }
    __shared__ float ssum[4], ssq[4];
    const int wave = tid >> 6, lane = tid & 63;
    if (lane == 0) { ssum[wave] = sum; ssq[wave] = sumsq; }
    __syncthreads();
    if (tid == 0) {
        float s0 = ssum[0] + ssum[1] + ssum[2] + ssum[3];
        float q0 = ssq[0] + ssq[1] + ssq[2] + ssq[3];
        const float invN = 1.0f / (float)(NB * S);
        float m = s0 * invN;
        float var = q0 * invN - m * m;
        float rstd = rsqrtf(var + EPS);
        float sc = gamma[c] * rstd;
        sc_sh[c] = sc;
        sc_sh[C + c] = beta[c] - m * sc;
    }
}

// ---------------- weight transposes ----------------
__global__ __launch_bounds__(256)
void wt_build(const float* __restrict__ w_qkv, const float* __restrict__ w_proj,
              u16* __restrict__ wT512, u16* __restrict__ wpT) {
    const int r0 = blockIdx.x, c = threadIdx.x;
    if (r0 < 512) {
        wT512[(size_t)r0 * 256 + c] = f2bf(w_qkv[(size_t)c * 768 + 256 + r0]);
    } else {
        const int o = r0 - 512;
        wpT[(size_t)o * 256 + c] = f2bf(w_proj[(size_t)c * 256 + o]);
    }
}

// ---------------- Stage 2: KV[z][s][jj] = sum_c XN[s][c]*wT512[jj][c] + b ----------------
__global__ __launch_bounds__(256)
void kvproj_gemm(const float* __restrict__ inp, const u16* __restrict__ wT512,
                 const float* __restrict__ b_qkv, const float* __restrict__ sc_sh,
                 u16* __restrict__ kvbuf) {
    __shared__ u16 Asm[128 * LDST];
    __shared__ u16 Bsm[128 * LDST];
    const int bid = blockIdx.x;
    const int wid = (bid & 7) * 288 + (bid >> 3);   // 2304 = 8*288
    const int jt = wid & 3;
    const int st = (wid >> 2) % 72;
    const int z  = wid / 288;

    const int tid = threadIdx.x;
    const int l = tid & 63, w = tid >> 6;
    const int m0 = (w >> 1) * 64, n0 = (w & 1) * 64;
    const int g = l >> 4, r = l & 15;

    const int rowA = tid & 127;
    const int half = (tid >> 7) * 16;

    const float* inpz = inp + (size_t)z * C * S + (size_t)st * 128 + rowA;
    const u16* wrow = wT512 + (size_t)(jt * 128 + rowA) * 256;

    f32x4 acc[4][4];
    #pragma unroll
    for (int i = 0; i < 4; ++i)
        #pragma unroll
        for (int j = 0; j < 4; ++j) acc[i][j] = (f32x4){0.f, 0.f, 0.f, 0.f};

    for (int k0 = 0; k0 < 256; k0 += 32) {
        {   // A: fused BN + transpose: XN^T tile [128 s][32 c]
            u32 pk[8];
            #pragma unroll
            for (int u = 0; u < 8; ++u) {
                const int c = k0 + half + u * 2;
                float x0 = inpz[(size_t)c * S];
                float x1 = inpz[(size_t)(c + 1) * S];
                u16 b0 = f2bf(fmaf(x0, sc_sh[c], sc_sh[C + c]));
                u16 b1 = f2bf(fmaf(x1, sc_sh[c + 1], sc_sh[C + c + 1]));
                pk[u] = (u32)b0 | ((u32)b1 << 16);
            }
            uint4 q0, q1;
            q0.x = pk[0]; q0.y = pk[1]; q0.z = pk[2]; q0.w = pk[3];
            q1.x = pk[4]; q1.y = pk[5]; q1.z = pk[6]; q1.w = pk[7];
            *(uint4*)&Asm[rowA * LDST + half] = q0;
            *(uint4*)&Asm[rowA * LDST + half + 8] = q1;
        }
        {   // B: wT512 tile (contiguous bf16)
            const uint4* p = (const uint4*)&wrow[k0 + half];
            *(uint4*)&Bsm[rowA * LDST + half] = p[0];
            *(uint4*)&Bsm[rowA * LDST + half + 8] = p[1];
        }
        __syncthreads();
        bf16x8 a[4], b[4];
        #pragma unroll
        for (int i = 0; i < 4; ++i) a[i] = *(const bf16x8*)&Asm[(m0 + i * 16 + r) * LDST + g * 8];
        #pragma unroll
        for (int j = 0; j < 4; ++j) b[j] = *(const bf16x8*)&Bsm[(n0 + j * 16 + r) * LDST + g * 8];
        #pragma unroll
        for (int i = 0; i < 4; ++i)
            #pragma unroll
            for (int j = 0; j < 4; ++j)
                acc[i][j] = __builtin_amdgcn_mfma_f32_16x16x32_bf16(a[i], b[j], acc[i][j], 0, 0, 0);
        __syncthreads();
    }
    #pragma unroll
    for (int i = 0; i < 4; ++i) {
        #pragma unroll
        for (int q = 0; q < 4; ++q) {
            const int s = st * 128 + m0 + i * 16 + g * 4 + q;
            u16* dst = kvbuf + ((size_t)z * S + s) * 512;
            #pragma unroll
            for (int j = 0; j < 4; ++j) {
                const int jj = jt * 128 + n0 + j * 16 + r;
                dst[jj] = f2bf(acc[i][j][q] + b_qkv[256 + jj]);
            }
        }
    }
}

// ---------------- Stage 3: kv[d][e] = sum_s K[s][d]*V[s][e] (split-s=8, atomics) ----------------
__global__ __launch_bounds__(256)
void kv_gemm(const u16* __restrict__ kvbuf, float* __restrict__ kv) {
    __shared__ u16 Asm[128 * LDST];
    __shared__ u16 Bsm[128 * LDST];
    const int bid = blockIdx.x;
    const int wid = (bid & 7) * 32 + (bid >> 3);   // 256 = 8*32
    const int et = wid & 1;
    const int dt = (wid >> 1) & 1;
    const int sp = (wid >> 2) & 7;
    const int z  = wid >> 5;

    const int tid = threadIdx.x;
    const int l = tid & 63, w = tid >> 6;
    const int m0 = (w >> 1) * 64, n0 = (w & 1) * 64;
    const int g = l >> 4, r = l & 15;

    const int rowL = tid & 127;
    const int isB = tid >> 7;
    const int col = isB ? (256 + et * 128 + rowL) : (dt * 128 + rowL);
    const u16* src = kvbuf + (size_t)z * S * 512 + col;
    u16* dstL = (isB ? Bsm : Asm) + rowL * LDST;

    f32x4 acc[4][4];
    #pragma unroll
    for (int i = 0; i < 4; ++i)
        #pragma unroll
        for (int j = 0; j < 4; ++j) acc[i][j] = (f32x4){0.f, 0.f, 0.f, 0.f};

    const int sbeg = sp * 1152;
    for (int s0 = sbeg; s0 < sbeg + 1152; s0 += 32) {
        u32 pk[16];
        #pragma unroll
        for (int u = 0; u < 16; ++u) {
            u16 a0 = src[(size_t)(s0 + 2 * u) * 512];
            u16 a1 = src[(size_t)(s0 + 2 * u + 1) * 512];
            pk[u] = (u32)a0 | ((u32)a1 << 16);
        }
        #pragma unroll
        for (int u = 0; u < 4; ++u) {
            uint4 q;
            q.x = pk[u * 4]; q.y = pk[u * 4 + 1]; q.z = pk[u * 4 + 2]; q.w = pk[u * 4 + 3];
            *(uint4*)&dstL[u * 8] = q;
        }
        __syncthreads();
        bf16x8 a[4], b[4];
        #pragma unroll
        for (int i = 0; i < 4; ++i) a[i] = *(const bf16x8*)&Asm[(m0 + i * 16 + r) * LDST + g * 8];
        #pragma unroll
        for (int j = 0; j < 4; ++j) b[j] = *(const bf16x8*)&Bsm[(n0 + j * 16 + r) * LDST + g * 8];
        #pragma unroll
        for (int i = 0; i < 4; ++i)
            #pragma unroll
            for (int j = 0; j < 4; ++j)
                acc[i][j] = __builtin_amdgcn_mfma_f32_16x16x32_bf16(a[i], b[j], acc[i][j], 0, 0, 0);
        __syncthreads();
    }
    float* kvz = kv + (size_t)z * 65536;
    #pragma unroll
    for (int i = 0; i < 4; ++i)
        #pragma unroll
        for (int q = 0; q < 4; ++q) {
            const int d = dt * 128 + m0 + i * 16 + g * 4 + q;
            #pragma unroll
            for (int j = 0; j < 4; ++j) {
                const int e = et * 128 + n0 + j * 16 + r;
                atomicAdd(&kvz[(size_t)d * 256 + e], acc[i][j][q]);
            }
        }
}

// ---------------- Stage 4a: Ac2[z][o][d] = sum_e wpT[o][e] * kv[z][d][e] ----------------
__global__ __launch_bounds__(256)
void ac2_gemm(const u16* __restrict__ wpT, const float* __restrict__ kv,
              u16* __restrict__ Ac2) {
    __shared__ u16 Asm[128 * LDST];
    __shared__ u16 Bsm[128 * LDST];
    const int bid = blockIdx.x;
    const int z = bid >> 2, ot = (bid >> 1) & 1, dt = bid & 1;

    const int tid = threadIdx.x;
    const int l = tid & 63, w = tid >> 6;
    const int m0 = (w >> 1) * 64, n0 = (w & 1) * 64;
    const int g = l >> 4, r = l & 15;

    const int rowL = tid & 127;
    const int half = (tid >> 7) * 16;

    const u16* arow = wpT + (size_t)(ot * 128 + rowL) * 256;
    const float* brow = kv + (size_t)z * 65536 + (size_t)(dt * 128 + rowL) * 256;

    f32x4 acc[4][4];
    #pragma unroll
    for (int i = 0; i < 4; ++i)
        #pragma unroll
        for (int j = 0; j < 4; ++j) acc[i][j] = (f32x4){0.f, 0.f, 0.f, 0.f};

    for (int k0 = 0; k0 < 256; k0 += 32) {
        {
            const uint4* p = (const uint4*)&arow[k0 + half];
            *(uint4*)&Asm[rowL * LDST + half] = p[0];
            *(uint4*)&Asm[rowL * LDST + half + 8] = p[1];
        }
        stage16f(brow + k0 + half, &Bsm[rowL * LDST + half]);
        __syncthreads();
        bf16x8 a[4], b[4];
        #pragma unroll
        for (int i = 0; i < 4; ++i) a[i] = *(const bf16x8*)&Asm[(m0 + i * 16 + r) * LDST + g * 8];
        #pragma unroll
        for (int j = 0; j < 4; ++j) b[j] = *(const bf16x8*)&Bsm[(n0 + j * 16 + r) * LDST + g * 8];
        #pragma unroll
        for (int i = 0; i < 4; ++i)
            #pragma unroll
            for (int j = 0; j < 4; ++j)
                acc[i][j] = __builtin_amdgcn_mfma_f32_16x16x32_bf16(a[i], b[j], acc[i][j], 0, 0, 0);
        __syncthreads();
    }
    u16* Az = Ac2 + (size_t)z * 65536;
    #pragma unroll
    for (int i = 0; i < 4; ++i)
        #pragma unroll
        for (int q = 0; q < 4; ++q) {
            const int o = ot * 128 + m0 + i * 16 + g * 4 + q;
            #pragma unroll
            for (int j = 0; j < 4; ++j) {
                const int d = dt * 128 + n0 + j * 16 + r;
                Az[(size_t)o * 256 + d] = f2bf(acc[i][j][q]);
            }
        }
}

// ---------------- Stage 4b: M[z][o][c] = sum_e wpT[o][e]*wv[c][e] + sum_d Ac2[o][d]*wq[c][d] ----------------
__global__ __launch_bounds__(256)
void m_gemm(const u16* __restrict__ wpT, const u16* __restrict__ Ac2,
            const float* __restrict__ w_qkv, u16* __restrict__ M) {
    __shared__ u16 Asm[128 * LDST];
    __shared__ u16 Bsm[128 * LDST];
    const int bid = blockIdx.x;
    const int z = bid >> 2, ot = (bid >> 1) & 1, ct = bid & 1;

    const int tid = threadIdx.x;
    const int l = tid & 63, w = tid >> 6;
    const int m0 = (w >> 1) * 64, n0 = (w & 1) * 64;
    const int g = l >> 4, r = l & 15;

    const int rowL = tid & 127;
    const int half = (tid >> 7) * 16;

    const u16* wprow = wpT + (size_t)(ot * 128 + rowL) * 256;
    const u16* acrow = Ac2 + (size_t)z * 65536 + (size_t)(ot * 128 + rowL) * 256;
    const float* qrow = w_qkv + (size_t)(ct * 128 + rowL) * 768;

    f32x4 acc[4][4];
    #pragma unroll
    for (int i = 0; i < 4; ++i)
        #pragma unroll
        for (int j = 0; j < 4; ++j) acc[i][j] = (f32x4){0.f, 0.f, 0.f, 0.f};

    for (int k0 = 0; k0 < 512; k0 += 32) {
        {
            const u16* arow = (k0 < 256) ? (wprow + k0) : (acrow + (k0 - 256));
            const uint4* p = (const uint4*)&arow[half];
            *(uint4*)&Asm[rowL * LDST + half] = p[0];
            *(uint4*)&Asm[rowL * LDST + half + 8] = p[1];
        }
        {
            const int off = (k0 < 256) ? (512 + k0) : (k0 - 256);
            stage16f(qrow + off + half, &Bsm[rowL * LDST + half]);
        }
        __syncthreads();
        bf16x8 a[4], b[4];
        #pragma unroll
        for (int i = 0; i < 4; ++i) a[i] = *(const bf16x8*)&Asm[(m0 + i * 16 + r) * LDST + g * 8];
        #pragma unroll
        for (int j = 0; j < 4; ++j) b[j] = *(const bf16x8*)&Bsm[(n0 + j * 16 + r) * LDST + g * 8];
        #pragma unroll
        for (int i = 0; i < 4; ++i)
            #pragma unroll
            for (int j = 0; j < 4; ++j)
                acc[i][j] = __builtin_amdgcn_mfma_f32_16x16x32_bf16(a[i], b[j], acc[i][j], 0, 0, 0);
        __syncthreads();
    }
    u16* Mz = M + (size_t)z * 65536;
    #pragma unroll
    for (int i = 0; i < 4; ++i)
        #pragma unroll
        for (int q = 0; q < 4; ++q) {
            const int o = ot * 128 + m0 + i * 16 + g * 4 + q;
            #pragma unroll
            for (int j = 0; j < 4; ++j) {
                const int c = ct * 128 + n0 + j * 16 + r;
                Mz[(size_t)o * 256 + c] = f2bf(acc[i][j][q]);
            }
        }
}

// ---------------- Stage 4c: constz ----------------
__global__ __launch_bounds__(256)
void cvec(const u16* __restrict__ wpT, const u16* __restrict__ Ac2,
          const float* __restrict__ b_qkv, const float* __restrict__ b_proj,
          float* __restrict__ constz) {
    const int z = blockIdx.x, o = threadIdx.x;
    const u16* wprow = wpT + (size_t)o * 256;
    const u16* acrow = Ac2 + (size_t)z * 65536 + (size_t)o * 256;
    float acc = b_proj[o];
    #pragma unroll 4
    for (int e = 0; e < 256; ++e) acc = fmaf(bf2f(wprow[e]), b_qkv[512 + e], acc);
    #pragma unroll 4
    for (int d = 0; d < 256; ++d) acc = fmaf(bf2f(acrow[d]), b_qkv[d], acc);
    constz[z * 256 + o] = acc;
}

// ---------------- Stage 5: OUT[o][s] = M[o][:] . xn[:][s] + constz[o] + inp[o][s] ----------------
__global__ __launch_bounds__(256)
void out_gemm(const u16* __restrict__ M, const float* __restrict__ inp,
              const float* __restrict__ sc_sh, const float* __restrict__ constz,
              float* __restrict__ out) {
    __shared__ u16 Asm[128 * LDST];
    __shared__ u16 Bsm[128 * LDST];
    const int bid = blockIdx.x;
    const int wid = (bid & 7) * 144 + (bid >> 3);   // 1152 = 8*144
    const int ot = wid & 1;
    const int st = (wid >> 1) % 72;
    const int z  = wid / 144;

    const int tid = threadIdx.x;
    const int l = tid & 63, w = tid >> 6;
    const int m0 = (w >> 1) * 64, n0 = (w & 1) * 64;
    const int g = l >> 4, r = l & 15;

    const int rowL = tid & 127;
    const int half = (tid >> 7) * 16;

    const u16* arow = M + (size_t)z * 65536 + (size_t)(ot * 128 + rowL) * 256;
    const float* inpz = inp + (size_t)z * C * S + (size_t)st * 128 + rowL;

    f32x4 acc[4][4];
    #pragma unroll
    for (int i = 0; i < 4; ++i)
        #pragma unroll
        for (int j = 0; j < 4; ++j) acc[i][j] = (f32x4){0.f, 0.f, 0.f, 0.f};

    for (int k0 = 0; k0 < 256; k0 += 32) {
        {   // A: M rows (contiguous bf16)
            const uint4* p = (const uint4*)&arow[k0 + half];
            *(uint4*)&Asm[rowL * LDST + half] = p[0];
            *(uint4*)&Asm[rowL * LDST + half + 8] = p[1];
        }
        {   // B: fused BN + transpose: XN^T tile [128 s][32 c]
            u32 pk[8];
            #pragma unroll
            for (int u = 0; u < 8; ++u) {
                const int c = k0 + half + u * 2;
                float x0 = inpz[(size_t)c * S];
                float x1 = inpz[(size_t)(c + 1) * S];
                u16 b0 = f2bf(fmaf(x0, sc_sh[c], sc_sh[C + c]));
                u16 b1 = f2bf(fmaf(x1, sc_sh[c + 1], sc_sh[C + c + 1]));
                pk[u] = (u32)b0 | ((u32)b1 << 16);
            }
            uint4 q0, q1;
            q0.x = pk[0]; q0.y = pk[1]; q0.z = pk[2]; q0.w = pk[3];
            q1.x = pk[4]; q1.y = pk[5]; q1.z = pk[6]; q1.w = pk[7];
            *(uint4*)&Bsm[rowL * LDST + half] = q0;
            *(uint4*)&Bsm[rowL * LDST + half + 8] = q1;
        }
        __syncthreads();
        bf16x8 a[4], b[4];
        #pragma unroll
        for (int i = 0; i < 4; ++i) a[i] = *(const bf16x8*)&Asm[(m0 + i * 16 + r) * LDST + g * 8];
        #pragma unroll
        for (int j = 0; j < 4; ++j) b[j] = *(const bf16x8*)&Bsm[(n0 + j * 16 + r) * LDST + g * 8];
        #pragma unroll
        for (int i = 0; i < 4; ++i)
            #pragma unroll
            for (int j = 0; j < 4; ++j)
                acc[i][j] = __builtin_amdgcn_mfma_f32_16x16x32_bf16(a[i], b[j], acc[i][j], 0, 0, 0);
        __syncthreads();
    }
    #pragma unroll
    for (int i = 0; i < 4; ++i) {
        #pragma unroll
        for (int q = 0; q < 4; ++q) {
            const int o = ot * 128 + m0 + i * 16 + g * 4 + q;
            const float cz = constz[z * 256 + o];
            const size_t base = ((size_t)z * C + o) * S + st * 128;
            #pragma unroll
            for (int j = 0; j < 4; ++j) {
                const int sl = n0 + j * 16 + r;
                out[base + sl] = acc[i][j][q] + cz + inp[base + sl];
            }
        }
    }
}

extern "C" void kernel_launch(void* const* d_in, const int* in_sizes, int n_in,
                              void* d_out, int out_size, void* d_ws, size_t ws_size,
                              hipStream_t stream) {
    const float* inp    = (const float*)d_in[0];
    const float* gamma  = (const float*)d_in[1];
    const float* beta   = (const float*)d_in[2];
    const float* w_qkv  = (const float*)d_in[3];
    const float* b_qkv  = (const float*)d_in[4];
    const float* w_proj = (const float*)d_in[5];
    const float* b_proj = (const float*)d_in[6];
    float* out = (float*)d_out;

    char* ws = (char*)d_ws;
    float* sc_sh = (float*)ws;
    u16*   wT512 = (u16*)(ws + WS_WT);
    u16*   wpT   = (u16*)(ws + WS_WPT);
    u16*   Ac2   = (u16*)(ws + WS_AC2);
    u16*   Mm    = (u16*)(ws + WS_M);
    float* cz    = (float*)(ws + WS_CZ);
    float* kv    = (float*)(ws + WS_KV);
    u16*   kvbuf = (u16*)(ws + WS_QKV);

    hipMemsetAsync(kv, 0, (size_t)NB * 256 * 256 * sizeof(float), stream);

    bn_stats<<<dim3(C), dim3(256), 0, stream>>>(inp, gamma, beta, sc_sh);
    wt_build<<<dim3(768), dim3(256), 0, stream>>>(w_qkv, w_proj, wT512, wpT);
    kvproj_gemm<<<dim3(2304), dim3(256), 0, stream>>>(inp, wT512, b_qkv, sc_sh, kvbuf);
    kv_gemm<<<dim3(256), dim3(256), 0, stream>>>(kvbuf, kv);
    ac2_gemm<<<dim3(32), dim3(256), 0, stream>>>(wpT, kv, Ac2);
    m_gemm<<<dim3(32), dim3(256), 0, stream>>>(wpT, Ac2, w_qkv, Mm);
    cvec<<<dim3(NB), dim3(256), 0, stream>>>(wpT, Ac2, b_qkv, b_proj, cz);
    out_gemm<<<dim3(1152), dim3(256), 0, stream>>>(Mm, inp, sc_sh, cz, out);
}

// Round 5
// 238.540 us; speedup vs baseline: 4.4737x; 1.0508x over previous
//
#include <hip/hip_runtime.h>
#include <hip/hip_bf16.h>
#include <stdint.h>

#define S 9216
#define C 256
#define NB 8
#define EPS 1e-5f
#define LDST 40   // LDS row stride in u16 (80B): reduced bank conflicts for b128 r/w
#define GSPLIT 24 // s-splits in gram kernel

typedef __attribute__((ext_vector_type(8))) short bf16x8;
typedef __attribute__((ext_vector_type(4))) float f32x4;
typedef unsigned short u16;
typedef unsigned int u32;

// ---------------- ws layout (bytes) ----------------
#define WS_SC   0          // sc_sh fp32 [512]
#define WS_RX   4096       // rx fp32 [8][256]
#define WS_U    16384      // u fp32 [8][256]
#define WS_W    24576      // w fp32 [8][256]
#define WS_CZ   32768      // constz fp32 [8][256]
#define WS_WT   40960      // wT512 bf16 [512][256] (rows 0-255: K-proj, 256-511: V-proj)
#define WS_WPT  303104     // wpT bf16 [256][256]
#define WS_GX   434176     // Gx fp32 [8][256][256]
#define WS_GB   2531328    // Gb bf16 [8][256][256]
#define WS_TT   3579904    // Tt bf16 [8][256][256]  (T^T[e][c])
#define WS_KV   4628480    // kv fp32 [8][256][256]
#define WS_AC2  6725632    // Ac2 bf16 [8][256][256]
#define WS_M    7774208    // M bf16 [8][256][256]

__device__ __forceinline__ u16 f2bf(float x) {
    union { float f; u32 u; } v; v.f = x;
    u32 r = v.u + 0x7FFFu + ((v.u >> 16) & 1u);
    return (u16)(r >> 16);
}
__device__ __forceinline__ float bf2f(u16 b) { return __uint_as_float((u32)b << 16); }

__device__ __forceinline__ void stage16f(const float* __restrict__ src, u16* __restrict__ dst) {
    const float4* p = (const float4*)src;
    float4 f0 = p[0], f1 = p[1], f2 = p[2], f3 = p[3];
    uint4 q0, q1;
    q0.x = (u32)f2bf(f0.x) | ((u32)f2bf(f0.y) << 16);
    q0.y = (u32)f2bf(f0.z) | ((u32)f2bf(f0.w) << 16);
    q0.z = (u32)f2bf(f1.x) | ((u32)f2bf(f1.y) << 16);
    q0.w = (u32)f2bf(f1.z) | ((u32)f2bf(f1.w) << 16);
    q1.x = (u32)f2bf(f2.x) | ((u32)f2bf(f2.y) << 16);
    q1.y = (u32)f2bf(f2.z) | ((u32)f2bf(f2.w) << 16);
    q1.z = (u32)f2bf(f3.x) | ((u32)f2bf(f3.y) << 16);
    q1.w = (u32)f2bf(f3.z) | ((u32)f2bf(f3.w) << 16);
    *(uint4*)dst = q0;
    *(uint4*)(dst + 8) = q1;
}

// stage + return sum of the 16 staged values (for row-sums)
__device__ __forceinline__ float stage16s(const float* __restrict__ src, u16* __restrict__ dst) {
    const float4* p = (const float4*)src;
    float4 f0 = p[0], f1 = p[1], f2 = p[2], f3 = p[3];
    uint4 q0, q1;
    q0.x = (u32)f2bf(f0.x) | ((u32)f2bf(f0.y) << 16);
    q0.y = (u32)f2bf(f0.z) | ((u32)f2bf(f0.w) << 16);
    q0.z = (u32)f2bf(f1.x) | ((u32)f2bf(f1.y) << 16);
    q0.w = (u32)f2bf(f1.z) | ((u32)f2bf(f1.w) << 16);
    q1.x = (u32)f2bf(f2.x) | ((u32)f2bf(f2.y) << 16);
    q1.y = (u32)f2bf(f2.z) | ((u32)f2bf(f2.w) << 16);
    q1.z = (u32)f2bf(f3.x) | ((u32)f2bf(f3.y) << 16);
    q1.w = (u32)f2bf(f3.z) | ((u32)f2bf(f3.w) << 16);
    *(uint4*)dst = q0;
    *(uint4*)(dst + 8) = q1;
    return (f0.x + f0.y + f0.z + f0.w) + (f1.x + f1.y + f1.z + f1.w)
         + (f2.x + f2.y + f2.z + f2.w) + (f3.x + f3.y + f3.z + f3.w);
}

// ---------------- weight transposes ----------------
__global__ __launch_bounds__(256)
void wt_build(const float* __restrict__ w_qkv, const float* __restrict__ w_proj,
              u16* __restrict__ wT512, u16* __restrict__ wpT) {
    const int r0 = blockIdx.x, c = threadIdx.x;
    if (r0 < 512) {
        wT512[(size_t)r0 * 256 + c] = f2bf(w_qkv[(size_t)c * 768 + 256 + r0]);
    } else {
        const int o = r0 - 512;
        wpT[(size_t)o * 256 + c] = f2bf(w_proj[(size_t)c * 256 + o]);
    }
}

// ---------------- Stage 1: Gx[z] = X_z X_z^T (raw Gram, fp32 atomics) + rx row-sums ----------------
// tiles: tp 0:(0,0) 1:(1,1) 2:(0,1)+mirror; split-s = GSPLIT
__global__ __launch_bounds__(256)
void gram(const float* __restrict__ inp, float* __restrict__ Gx, float* __restrict__ rx) {
    __shared__ u16 Asm[128 * LDST];
    __shared__ u16 Bsm[128 * LDST];
    const int bid = blockIdx.x;
    const int wid = (bid & 7) * 72 + (bid >> 3);   // 576 = 8*72
    const int z   = wid / 72;
    const int rem = wid % 72;
    const int tp  = rem / GSPLIT;
    const int sp  = rem % GSPLIT;
    const int ct  = (tp == 1) ? 1 : 0;
    const int ctp = (tp == 0) ? 0 : 1;
    const bool diag = (tp < 2);

    const int tid = threadIdx.x;
    const int l = tid & 63, w = tid >> 6;
    const int m0 = (w >> 1) * 64, n0 = (w & 1) * 64;
    const int g = l >> 4, r = l & 15;
    const int rowL = tid & 127;
    const int half = (tid >> 7) * 16;

    const float* arow = inp + ((size_t)(z * C + ct * 128 + rowL)) * S;
    const float* brow = inp + ((size_t)(z * C + ctp * 128 + rowL)) * S;

    f32x4 acc[4][4];
    #pragma unroll
    for (int i = 0; i < 4; ++i)
        #pragma unroll
        for (int j = 0; j < 4; ++j) acc[i][j] = (f32x4){0.f, 0.f, 0.f, 0.f};
    float rsum = 0.f;

    const int sbeg = sp * (S / GSPLIT);
    for (int s0 = sbeg; s0 < sbeg + (S / GSPLIT); s0 += 32) {
        rsum += stage16s(arow + s0 + half, &Asm[rowL * LDST + half]);
        if (!diag) stage16f(brow + s0 + half, &Bsm[rowL * LDST + half]);
        __syncthreads();
        const u16* Bb = diag ? Asm : Bsm;
        bf16x8 a[4], b[4];
        #pragma unroll
        for (int i = 0; i < 4; ++i) a[i] = *(const bf16x8*)&Asm[(m0 + i * 16 + r) * LDST + g * 8];
        #pragma unroll
        for (int j = 0; j < 4; ++j) b[j] = *(const bf16x8*)&Bb[(n0 + j * 16 + r) * LDST + g * 8];
        #pragma unroll
        for (int i = 0; i < 4; ++i)
            #pragma unroll
            for (int j = 0; j < 4; ++j)
                acc[i][j] = __builtin_amdgcn_mfma_f32_16x16x32_bf16(a[i], b[j], acc[i][j], 0, 0, 0);
        __syncthreads();
    }
    float* Gxz = Gx + (size_t)z * 65536;
    #pragma unroll
    for (int i = 0; i < 4; ++i)
        #pragma unroll
        for (int q = 0; q < 4; ++q) {
            const int row = ct * 128 + m0 + i * 16 + g * 4 + q;
            #pragma unroll
            for (int j = 0; j < 4; ++j) {
                const int col = ctp * 128 + n0 + j * 16 + r;
                atomicAdd(&Gxz[(size_t)row * 256 + col], acc[i][j][q]);
                if (!diag) atomicAdd(&Gxz[(size_t)col * 256 + row], acc[i][j][q]);
            }
        }
    if (diag) atomicAdd(&rx[z * 256 + ct * 128 + rowL], rsum);
}

// ---------------- BN finalize: sc/sh from Gx diag + rx ----------------
__global__ __launch_bounds__(256)
void bn_fin(const float* __restrict__ Gx, const float* __restrict__ rx,
            const float* __restrict__ gamma, const float* __restrict__ beta,
            float* __restrict__ sc_sh) {
    const int c = threadIdx.x;
    float s = 0.f, q = 0.f;
    #pragma unroll
    for (int z = 0; z < NB; ++z) {
        s += rx[z * 256 + c];
        q += Gx[(size_t)z * 65536 + (size_t)c * 257];
    }
    const float invN = 1.0f / (float)(NB * S);
    float m = s * invN;
    float var = q * invN - m * m;
    float rstd = rsqrtf(var + EPS);
    float sc = gamma[c] * rstd;
    sc_sh[c] = sc;
    sc_sh[C + c] = beta[c] - m * sc;
}

// ---------------- Gb[z][c][c'] bf16 = (XN XN^T) via affine of Gx ----------------
__global__ __launch_bounds__(256)
void g_build(const float* __restrict__ Gx, const float* __restrict__ rx,
             const float* __restrict__ sc_sh, u16* __restrict__ Gb) {
    const int flat = blockIdx.x * 256 + threadIdx.x;   // 512 blocks, 4 elems/thread
    const int z = flat >> 14;
    const int r2 = flat & 16383;
    const int c = r2 >> 6;
    const int c4 = (r2 & 63) * 4;
    const float sc_c = sc_sh[c], sh_c = sc_sh[C + c];
    const float rxc = rx[z * 256 + c];
    float4 gx = *(const float4*)&Gx[(size_t)z * 65536 + (size_t)c * 256 + c4];
    u16 o[4];
    #pragma unroll
    for (int e = 0; e < 4; ++e) {
        const int cp = c4 + e;
        const float gxe = (&gx.x)[e];
        float v = sc_c * sc_sh[cp] * gxe + sc_c * sc_sh[C + cp] * rxc
                + sh_c * sc_sh[cp] * rx[z * 256 + cp] + 9216.f * sh_c * sc_sh[C + cp];
        o[e] = f2bf(v);
    }
    *(uint2*)&Gb[(size_t)z * 65536 + (size_t)c * 256 + c4] = *(uint2*)o;
}

// ---------------- u[z][d] = wk^T rsn, w[z][e] = wv^T rsn ----------------
__global__ __launch_bounds__(256)
void uv_vec(const float* __restrict__ rx, const float* __restrict__ sc_sh,
            const u16* __restrict__ wT512, float* __restrict__ uvec, float* __restrict__ wvec) {
    const int z = blockIdx.x, t = threadIdx.x;
    __shared__ float rsn[256];
    rsn[t] = sc_sh[t] * rx[z * 256 + t] + 9216.f * sc_sh[C + t];
    __syncthreads();
    const u16* krow = wT512 + (size_t)t * 256;
    const u16* vrow = wT512 + (size_t)(256 + t) * 256;
    float au = 0.f, aw = 0.f;
    for (int cb = 0; cb < 256; cb += 8) {
        uint4 kp = *(const uint4*)&krow[cb];
        uint4 vp = *(const uint4*)&vrow[cb];
        const u16* kk = (const u16*)&kp;
        const u16* vv = (const u16*)&vp;
        #pragma unroll
        for (int u = 0; u < 8; ++u) {
            au = fmaf(bf2f(kk[u]), rsn[cb + u], au);
            aw = fmaf(bf2f(vv[u]), rsn[cb + u], aw);
        }
    }
    uvec[z * 256 + t] = au;
    wvec[z * 256 + t] = aw;
}

// ---------------- Tt[z][e][c] = sum_c' wvT[e][c'] * G[z][c][c'] ----------------
__global__ __launch_bounds__(256)
void t_gemm(const u16* __restrict__ wT512, const u16* __restrict__ Gb, u16* __restrict__ Tt) {
    __shared__ u16 Asm[128 * LDST];
    __shared__ u16 Bsm[128 * LDST];
    const int bid = blockIdx.x;
    const int z = bid >> 2, et = (bid >> 1) & 1, ct = bid & 1;

    const int tid = threadIdx.x;
    const int l = tid & 63, w = tid >> 6;
    const int m0 = (w >> 1) * 64, n0 = (w & 1) * 64;
    const int g = l >> 4, r = l & 15;
    const int rowL = tid & 127;
    const int half = (tid >> 7) * 16;

    const u16* arow = wT512 + (size_t)(256 + et * 128 + rowL) * 256;
    const u16* brow = Gb + (size_t)z * 65536 + (size_t)(ct * 128 + rowL) * 256;

    f32x4 acc[4][4];
    #pragma unroll
    for (int i = 0; i < 4; ++i)
        #pragma unroll
        for (int j = 0; j < 4; ++j) acc[i][j] = (f32x4){0.f, 0.f, 0.f, 0.f};

    for (int k0 = 0; k0 < 256; k0 += 32) {
        {
            const uint4* p = (const uint4*)&arow[k0 + half];
            *(uint4*)&Asm[rowL * LDST + half] = p[0];
            *(uint4*)&Asm[rowL * LDST + half + 8] = p[1];
        }
        {
            const uint4* p = (const uint4*)&brow[k0 + half];
            *(uint4*)&Bsm[rowL * LDST + half] = p[0];
            *(uint4*)&Bsm[rowL * LDST + half + 8] = p[1];
        }
        __syncthreads();
        bf16x8 a[4], b[4];
        #pragma unroll
        for (int i = 0; i < 4; ++i) a[i] = *(const bf16x8*)&Asm[(m0 + i * 16 + r) * LDST + g * 8];
        #pragma unroll
        for (int j = 0; j < 4; ++j) b[j] = *(const bf16x8*)&Bsm[(n0 + j * 16 + r) * LDST + g * 8];
        #pragma unroll
        for (int i = 0; i < 4; ++i)
            #pragma unroll
            for (int j = 0; j < 4; ++j)
                acc[i][j] = __builtin_amdgcn_mfma_f32_16x16x32_bf16(a[i], b[j], acc[i][j], 0, 0, 0);
        __syncthreads();
    }
    u16* Tz = Tt + (size_t)z * 65536;
    #pragma unroll
    for (int i = 0; i < 4; ++i)
        #pragma unroll
        for (int q = 0; q < 4; ++q) {
            const int e = et * 128 + m0 + i * 16 + g * 4 + q;
            #pragma unroll
            for (int j = 0; j < 4; ++j) {
                const int c = ct * 128 + n0 + j * 16 + r;
                Tz[(size_t)e * 256 + c] = f2bf(acc[i][j][q]);
            }
        }
}

// ---------------- kv[z][d][e] = sum_c wkT[d][c]*Tt[e][c] + u[d]*bv[e] + bk[d]*(w[e]+S*bv[e]) ----------------
__global__ __launch_bounds__(256)
void kv2_gemm(const u16* __restrict__ wT512, const u16* __restrict__ Tt,
              const float* __restrict__ uvec, const float* __restrict__ wvec,
              const float* __restrict__ b_qkv, float* __restrict__ kv) {
    __shared__ u16 Asm[128 * LDST];
    __shared__ u16 Bsm[128 * LDST];
    const int bid = blockIdx.x;
    const int z = bid >> 2, dt = (bid >> 1) & 1, et = bid & 1;

    const int tid = threadIdx.x;
    const int l = tid & 63, w = tid >> 6;
    const int m0 = (w >> 1) * 64, n0 = (w & 1) * 64;
    const int g = l >> 4, r = l & 15;
    const int rowL = tid & 127;
    const int half = (tid >> 7) * 16;

    const u16* arow = wT512 + (size_t)(dt * 128 + rowL) * 256;
    const u16* brow = Tt + (size_t)z * 65536 + (size_t)(et * 128 + rowL) * 256;

    f32x4 acc[4][4];
    #pragma unroll
    for (int i = 0; i < 4; ++i)
        #pragma unroll
        for (int j = 0; j < 4; ++j) acc[i][j] = (f32x4){0.f, 0.f, 0.f, 0.f};

    for (int k0 = 0; k0 < 256; k0 += 32) {
        {
            const uint4* p = (const uint4*)&arow[k0 + half];
            *(uint4*)&Asm[rowL * LDST + half] = p[0];
            *(uint4*)&Asm[rowL * LDST + half + 8] = p[1];
        }
        {
            const uint4* p = (const uint4*)&brow[k0 + half];
            *(uint4*)&Bsm[rowL * LDST + half] = p[0];
            *(uint4*)&Bsm[rowL * LDST + half + 8] = p[1];
        }
        __syncthreads();
        bf16x8 a[4], b[4];
        #pragma unroll
        for (int i = 0; i < 4; ++i) a[i] = *(const bf16x8*)&Asm[(m0 + i * 16 + r) * LDST + g * 8];
        #pragma unroll
        for (int j = 0; j < 4; ++j) b[j] = *(const bf16x8*)&Bsm[(n0 + j * 16 + r) * LDST + g * 8];
        #pragma unroll
        for (int i = 0; i < 4; ++i)
            #pragma unroll
            for (int j = 0; j < 4; ++j)
                acc[i][j] = __builtin_amdgcn_mfma_f32_16x16x32_bf16(a[i], b[j], acc[i][j], 0, 0, 0);
        __syncthreads();
    }
    float* kvz = kv + (size_t)z * 65536;
    #pragma unroll
    for (int i = 0; i < 4; ++i)
        #pragma unroll
        for (int q = 0; q < 4; ++q) {
            const int d = dt * 128 + m0 + i * 16 + g * 4 + q;
            const float bk = b_qkv[256 + d];
            const float ud = uvec[z * 256 + d];
            #pragma unroll
            for (int j = 0; j < 4; ++j) {
                const int e = et * 128 + n0 + j * 16 + r;
                const float bv = b_qkv[512 + e];
                kvz[(size_t)d * 256 + e] = acc[i][j][q] + ud * bv + bk * (wvec[z * 256 + e] + 9216.f * bv);
            }
        }
}

// ---------------- Ac2[z][o][d] = sum_e wpT[o][e] * kv[z][d][e] ----------------
__global__ __launch_bounds__(256)
void ac2_gemm(const u16* __restrict__ wpT, const float* __restrict__ kv,
              u16* __restrict__ Ac2) {
    __shared__ u16 Asm[128 * LDST];
    __shared__ u16 Bsm[128 * LDST];
    const int bid = blockIdx.x;
    const int z = bid >> 2, ot = (bid >> 1) & 1, dt = bid & 1;

    const int tid = threadIdx.x;
    const int l = tid & 63, w = tid >> 6;
    const int m0 = (w >> 1) * 64, n0 = (w & 1) * 64;
    const int g = l >> 4, r = l & 15;
    const int rowL = tid & 127;
    const int half = (tid >> 7) * 16;

    const u16* arow = wpT + (size_t)(ot * 128 + rowL) * 256;
    const float* brow = kv + (size_t)z * 65536 + (size_t)(dt * 128 + rowL) * 256;

    f32x4 acc[4][4];
    #pragma unroll
    for (int i = 0; i < 4; ++i)
        #pragma unroll
        for (int j = 0; j < 4; ++j) acc[i][j] = (f32x4){0.f, 0.f, 0.f, 0.f};

    for (int k0 = 0; k0 < 256; k0 += 32) {
        {
            const uint4* p = (const uint4*)&arow[k0 + half];
            *(uint4*)&Asm[rowL * LDST + half] = p[0];
            *(uint4*)&Asm[rowL * LDST + half + 8] = p[1];
        }
        stage16f(brow + k0 + half, &Bsm[rowL * LDST + half]);
        __syncthreads();
        bf16x8 a[4], b[4];
        #pragma unroll
        for (int i = 0; i < 4; ++i) a[i] = *(const bf16x8*)&Asm[(m0 + i * 16 + r) * LDST + g * 8];
        #pragma unroll
        for (int j = 0; j < 4; ++j) b[j] = *(const bf16x8*)&Bsm[(n0 + j * 16 + r) * LDST + g * 8];
        #pragma unroll
        for (int i = 0; i < 4; ++i)
            #pragma unroll
            for (int j = 0; j < 4; ++j)
                acc[i][j] = __builtin_amdgcn_mfma_f32_16x16x32_bf16(a[i], b[j], acc[i][j], 0, 0, 0);
        __syncthreads();
    }
    u16* Az = Ac2 + (size_t)z * 65536;
    #pragma unroll
    for (int i = 0; i < 4; ++i)
        #pragma unroll
        for (int q = 0; q < 4; ++q) {
            const int o = ot * 128 + m0 + i * 16 + g * 4 + q;
            #pragma unroll
            for (int j = 0; j < 4; ++j) {
                const int d = dt * 128 + n0 + j * 16 + r;
                Az[(size_t)o * 256 + d] = f2bf(acc[i][j][q]);
            }
        }
}

// ---------------- M[z][o][c] = sum_e wpT[o][e]*wv[c][e] + sum_d Ac2[o][d]*wq[c][d] ----------------
__global__ __launch_bounds__(256)
void m_gemm(const u16* __restrict__ wpT, const u16* __restrict__ Ac2,
            const float* __restrict__ w_qkv, u16* __restrict__ M) {
    __shared__ u16 Asm[128 * LDST];
    __shared__ u16 Bsm[128 * LDST];
    const int bid = blockIdx.x;
    const int z = bid >> 2, ot = (bid >> 1) & 1, ct = bid & 1;

    const int tid = threadIdx.x;
    const int l = tid & 63, w = tid >> 6;
    const int m0 = (w >> 1) * 64, n0 = (w & 1) * 64;
    const int g = l >> 4, r = l & 15;
    const int rowL = tid & 127;
    const int half = (tid >> 7) * 16;

    const u16* wprow = wpT + (size_t)(ot * 128 + rowL) * 256;
    const u16* acrow = Ac2 + (size_t)z * 65536 + (size_t)(ot * 128 + rowL) * 256;
    const float* qrow = w_qkv + (size_t)(ct * 128 + rowL) * 768;

    f32x4 acc[4][4];
    #pragma unroll
    for (int i = 0; i < 4; ++i)
        #pragma unroll
        for (int j = 0; j < 4; ++j) acc[i][j] = (f32x4){0.f, 0.f, 0.f, 0.f};

    for (int k0 = 0; k0 < 512; k0 += 32) {
        {
            const u16* arow = (k0 < 256) ? (wprow + k0) : (acrow + (k0 - 256));
            const uint4* p = (const uint4*)&arow[half];
            *(uint4*)&Asm[rowL * LDST + half] = p[0];
            *(uint4*)&Asm[rowL * LDST + half + 8] = p[1];
        }
        {
            const int off = (k0 < 256) ? (512 + k0) : (k0 - 256);
            stage16f(qrow + off + half, &Bsm[rowL * LDST + half]);
        }
        __syncthreads();
        bf16x8 a[4], b[4];
        #pragma unroll
        for (int i = 0; i < 4; ++i) a[i] = *(const bf16x8*)&Asm[(m0 + i * 16 + r) * LDST + g * 8];
        #pragma unroll
        for (int j = 0; j < 4; ++j) b[j] = *(const bf16x8*)&Bsm[(n0 + j * 16 + r) * LDST + g * 8];
        #pragma unroll
        for (int i = 0; i < 4; ++i)
            #pragma unroll
            for (int j = 0; j < 4; ++j)
                acc[i][j] = __builtin_amdgcn_mfma_f32_16x16x32_bf16(a[i], b[j], acc[i][j], 0, 0, 0);
        __syncthreads();
    }
    u16* Mz = M + (size_t)z * 65536;
    #pragma unroll
    for (int i = 0; i < 4; ++i)
        #pragma unroll
        for (int q = 0; q < 4; ++q) {
            const int o = ot * 128 + m0 + i * 16 + g * 4 + q;
            #pragma unroll
            for (int j = 0; j < 4; ++j) {
                const int c = ct * 128 + n0 + j * 16 + r;
                Mz[(size_t)o * 256 + c] = f2bf(acc[i][j][q]);
            }
        }
}

// ---------------- constz ----------------
__global__ __launch_bounds__(256)
void cvec(const u16* __restrict__ wpT, const u16* __restrict__ Ac2,
          const float* __restrict__ b_qkv, const float* __restrict__ b_proj,
          float* __restrict__ constz) {
    const int z = blockIdx.x, o = threadIdx.x;
    const u16* wprow = wpT + (size_t)o * 256;
    const u16* acrow = Ac2 + (size_t)z * 65536 + (size_t)o * 256;
    float acc = b_proj[o];
    #pragma unroll 4
    for (int e = 0; e < 256; ++e) acc = fmaf(bf2f(wprow[e]), b_qkv[512 + e], acc);
    #pragma unroll 4
    for (int d = 0; d < 256; ++d) acc = fmaf(bf2f(acrow[d]), b_qkv[d], acc);
    constz[z * 256 + o] = acc;
}

// ---------------- OUT[o][s] = M[o][:] . xn[:][s] + constz[o] + inp[o][s] ----------------
__global__ __launch_bounds__(256)
void out_gemm(const u16* __restrict__ M, const float* __restrict__ inp,
              const float* __restrict__ sc_sh, const float* __restrict__ constz,
              float* __restrict__ out) {
    __shared__ u16 Asm[128 * LDST];
    __shared__ u16 Bsm[128 * LDST];
    const int bid = blockIdx.x;
    const int wid = (bid & 7) * 144 + (bid >> 3);   // 1152 = 8*144
    const int ot = wid & 1;
    const int st = (wid >> 1) % 72;
    const int z  = wid / 144;

    const int tid = threadIdx.x;
    const int l = tid & 63, w = tid >> 6;
    const int m0 = (w >> 1) * 64, n0 = (w & 1) * 64;
    const int g = l >> 4, r = l & 15;
    const int rowL = tid & 127;
    const int half = (tid >> 7) * 16;

    const u16* arow = M + (size_t)z * 65536 + (size_t)(ot * 128 + rowL) * 256;
    const float* inpz = inp + (size_t)z * C * S + (size_t)st * 128 + rowL;

    f32x4 acc[4][4];
    #pragma unroll
    for (int i = 0; i < 4; ++i)
        #pragma unroll
        for (int j = 0; j < 4; ++j) acc[i][j] = (f32x4){0.f, 0.f, 0.f, 0.f};

    for (int k0 = 0; k0 < 256; k0 += 32) {
        {
            const uint4* p = (const uint4*)&arow[k0 + half];
            *(uint4*)&Asm[rowL * LDST + half] = p[0];
            *(uint4*)&Asm[rowL * LDST + half + 8] = p[1];
        }
        {
            u32 pk[8];
            #pragma unroll
            for (int u = 0; u < 8; ++u) {
                const int c = k0 + half + u * 2;
                float x0 = inpz[(size_t)c * S];
                float x1 = inpz[(size_t)(c + 1) * S];
                u16 b0 = f2bf(fmaf(x0, sc_sh[c], sc_sh[C + c]));
                u16 b1 = f2bf(fmaf(x1, sc_sh[c + 1], sc_sh[C + c + 1]));
                pk[u] = (u32)b0 | ((u32)b1 << 16);
            }
            uint4 q0, q1;
            q0.x = pk[0]; q0.y = pk[1]; q0.z = pk[2]; q0.w = pk[3];
            q1.x = pk[4]; q1.y = pk[5]; q1.z = pk[6]; q1.w = pk[7];
            *(uint4*)&Bsm[rowL * LDST + half] = q0;
            *(uint4*)&Bsm[rowL * LDST + half + 8] = q1;
        }
        __syncthreads();
        bf16x8 a[4], b[4];
        #pragma unroll
        for (int i = 0; i < 4; ++i) a[i] = *(const bf16x8*)&Asm[(m0 + i * 16 + r) * LDST + g * 8];
        #pragma unroll
        for (int j = 0; j < 4; ++j) b[j] = *(const bf16x8*)&Bsm[(n0 + j * 16 + r) * LDST + g * 8];
        #pragma unroll
        for (int i = 0; i < 4; ++i)
            #pragma unroll
            for (int j = 0; j < 4; ++j)
                acc[i][j] = __builtin_amdgcn_mfma_f32_16x16x32_bf16(a[i], b[j], acc[i][j], 0, 0, 0);
        __syncthreads();
    }
    #pragma unroll
    for (int i = 0; i < 4; ++i) {
        #pragma unroll
        for (int q = 0; q < 4; ++q) {
            const int o = ot * 128 + m0 + i * 16 + g * 4 + q;
            const float cz = constz[z * 256 + o];
            const size_t base = ((size_t)z * C + o) * S + st * 128;
            #pragma unroll
            for (int j = 0; j < 4; ++j) {
                const int sl = n0 + j * 16 + r;
                out[base + sl] = acc[i][j][q] + cz + inp[base + sl];
            }
        }
    }
}

extern "C" void kernel_launch(void* const* d_in, const int* in_sizes, int n_in,
                              void* d_out, int out_size, void* d_ws, size_t ws_size,
                              hipStream_t stream) {
    const float* inp    = (const float*)d_in[0];
    const float* gamma  = (const float*)d_in[1];
    const float* beta   = (const float*)d_in[2];
    const float* w_qkv  = (const float*)d_in[3];
    const float* b_qkv  = (const float*)d_in[4];
    const float* w_proj = (const float*)d_in[5];
    const float* b_proj = (const float*)d_in[6];
    float* out = (float*)d_out;

    char* ws = (char*)d_ws;
    float* sc_sh = (float*)(ws + WS_SC);
    float* rx    = (float*)(ws + WS_RX);
    float* uvec  = (float*)(ws + WS_U);
    float* wvec  = (float*)(ws + WS_W);
    float* cz    = (float*)(ws + WS_CZ);
    u16*   wT512 = (u16*)(ws + WS_WT);
    u16*   wpT   = (u16*)(ws + WS_WPT);
    float* Gx    = (float*)(ws + WS_GX);
    u16*   Gb    = (u16*)(ws + WS_GB);
    u16*   Tt    = (u16*)(ws + WS_TT);
    float* kv    = (float*)(ws + WS_KV);
    u16*   Ac2   = (u16*)(ws + WS_AC2);
    u16*   Mm    = (u16*)(ws + WS_M);

    hipMemsetAsync(Gx, 0, (size_t)NB * 65536 * sizeof(float), stream);
    hipMemsetAsync(rx, 0, (size_t)NB * 256 * sizeof(float), stream);

    wt_build<<<dim3(768), dim3(256), 0, stream>>>(w_qkv, w_proj, wT512, wpT);
    gram<<<dim3(576), dim3(256), 0, stream>>>(inp, Gx, rx);
    bn_fin<<<dim3(1), dim3(256), 0, stream>>>(Gx, rx, gamma, beta, sc_sh);
    g_build<<<dim3(512), dim3(256), 0, stream>>>(Gx, rx, sc_sh, Gb);
    uv_vec<<<dim3(NB), dim3(256), 0, stream>>>(rx, sc_sh, wT512, uvec, wvec);
    t_gemm<<<dim3(32), dim3(256), 0, stream>>>(wT512, Gb, Tt);
    kv2_gemm<<<dim3(32), dim3(256), 0, stream>>>(wT512, Tt, uvec, wvec, b_qkv, kv);
    ac2_gemm<<<dim3(32), dim3(256), 0, stream>>>(wpT, kv, Ac2);
    m_gemm<<<dim3(32), dim3(256), 0, stream>>>(wpT, Ac2, w_qkv, Mm);
    cvec<<<dim3(NB), dim3(256), 0, stream>>>(wpT, Ac2, b_qkv, b_proj, cz);
    out_gemm<<<dim3(1152), dim3(256), 0, stream>>>(Mm, inp, sc_sh, cz, out);
}

// Round 6
// 227.772 us; speedup vs baseline: 4.6852x; 1.0473x over previous
//
#include <hip/hip_runtime.h>
#include <hip/hip_bf16.h>
#include <stdint.h>

#define S 9216
#define C 256
#define NB 8
#define EPS 1e-5f
#define LDST 40     // LDS row stride (u16) for out_gemm B tile
#define GSPLIT 12   // s-splits in gram

typedef __attribute__((ext_vector_type(8))) short bf16x8;
typedef __attribute__((ext_vector_type(4))) float f32x4;
typedef unsigned short u16;
typedef unsigned int u32;

// ---------------- ws layout (bytes) ----------------
#define WS_SC   0          // sc_sh fp32 [512]
#define WS_RX   4096       // rx fp32 [8][256]
#define WS_U    16384      // u fp32 [8][256]
#define WS_PV   28672      // pv fp32 [8][256]
#define WS_P1   40960      // p1 fp32 [256]
#define WS_CZ   45056      // constz fp32 [8][256]
#define WS_WKT  65536      // wkT bf16 [256][256]
#define WS_WPT  262144     // wpT bf16 [256][256]
#define WS_WPV  458752     // Wpv bf16 [256][256]
#define WS_GX   1048576    // Gx fp32 [8][256][256]
#define WS_GB   4194304    // Gb bf16 [8][256][256]
#define WS_T1   5242880    // T1 bf16 [8][256][256]
#define WS_AC2  6291456    // Ac2 bf16 [8][256][256]
#define WS_M    7340032    // M bf16 [8][256][256]

__device__ __forceinline__ float bf2f(u16 b) { return __uint_as_float((u32)b << 16); }
__device__ __forceinline__ u16 cvt1(float x) {
    __hip_bfloat16 h = __float2bfloat16(x);
    return *(u16*)&h;
}
__device__ __forceinline__ bf16x8 pack8(float4 a, float4 b) {
    union { bf16x8 v; u16 h[8]; } u;
    u.h[0] = cvt1(a.x); u.h[1] = cvt1(a.y); u.h[2] = cvt1(a.z); u.h[3] = cvt1(a.w);
    u.h[4] = cvt1(b.x); u.h[5] = cvt1(b.y); u.h[6] = cvt1(b.z); u.h[7] = cvt1(b.w);
    return u.v;
}

// ---------------- weight transposes: wkT[d][c]=wq[c][256+d], wpT[o][e]=wp[e][o] ----------------
__global__ __launch_bounds__(256)
void wt_build(const float* __restrict__ w_qkv, const float* __restrict__ w_proj,
              u16* __restrict__ wkT, u16* __restrict__ wpT) {
    const int r0 = blockIdx.x, c = threadIdx.x;
    if (r0 < 256) {
        wkT[(size_t)r0 * 256 + c] = cvt1(w_qkv[(size_t)c * 768 + 256 + r0]);
    } else {
        const int o = r0 - 256;
        wpT[(size_t)o * 256 + c] = cvt1(w_proj[(size_t)c * 256 + o]);
    }
}

// ---------------- Wpv[o][c] = sum_e wpT[o][e] * wv[c][e] (wv[c][e]=w_qkv[c][512+e]) ----------------
// 16 blocks: 4x4 tiles of 64x64; direct-frag, no LDS
__global__ __launch_bounds__(256)
void wpv_gemm(const u16* __restrict__ wpT, const float* __restrict__ w_qkv,
              u16* __restrict__ Wpv) {
    const int bid = blockIdx.x;
    const int ot = bid >> 2, ct = bid & 3;
    const int tid = threadIdx.x;
    const int w = tid >> 6, l = tid & 63, g = l >> 4, r = l & 15;
    const int wr = w >> 1, wc = w & 1;
    const int mb = ot * 64 + wr * 32, nb = ct * 64 + wc * 32;

    f32x4 acc[2][2];
    #pragma unroll
    for (int i = 0; i < 2; ++i)
        #pragma unroll
        for (int j = 0; j < 2; ++j) acc[i][j] = (f32x4){0.f, 0.f, 0.f, 0.f};

    for (int k0 = 0; k0 < 256; k0 += 32) {
        bf16x8 a[2], b[2];
        #pragma unroll
        for (int i = 0; i < 2; ++i)
            a[i] = *(const bf16x8*)&wpT[(size_t)(mb + i * 16 + r) * 256 + k0 + g * 8];
        #pragma unroll
        for (int j = 0; j < 2; ++j) {
            const float* p = w_qkv + (size_t)(nb + j * 16 + r) * 768 + 512 + k0 + g * 8;
            b[j] = pack8(*(const float4*)p, *(const float4*)(p + 4));
        }
        #pragma unroll
        for (int i = 0; i < 2; ++i)
            #pragma unroll
            for (int j = 0; j < 2; ++j)
                acc[i][j] = __builtin_amdgcn_mfma_f32_16x16x32_bf16(a[i], b[j], acc[i][j], 0, 0, 0);
    }
    #pragma unroll
    for (int i = 0; i < 2; ++i)
        #pragma unroll
        for (int q = 0; q < 4; ++q) {
            const int row = mb + i * 16 + g * 4 + q;
            #pragma unroll
            for (int j = 0; j < 2; ++j)
                Wpv[(size_t)row * 256 + nb + j * 16 + r] = cvt1(acc[i][j][q]);
        }
}

// ---------------- gram: Gx[z] = X_z X_z^T + rx row sums; direct-frag, atomics ----------------
__global__ __launch_bounds__(256)
void gram(const float* __restrict__ inp, float* __restrict__ Gx, float* __restrict__ rx) {
    const int bid = blockIdx.x;
    const int wid = (bid & 7) * 120 + (bid >> 3);   // 960 = 8*120
    const int z = wid / 120;
    const int rem = wid % 120;
    const int tile = rem / GSPLIT;
    const int sp = rem % GSPLIT;
    int ct, cp;
    if (tile < 4) { ct = tile; cp = tile; }
    else {
        const int u = tile - 4;
        if (u < 3) { ct = 0; cp = u + 1; }
        else if (u < 5) { ct = 1; cp = u - 1; }
        else { ct = 2; cp = 3; }
    }
    const bool diag = (ct == cp);

    const int tid = threadIdx.x;
    const int w = tid >> 6, l = tid & 63, g = l >> 4, r = l & 15;
    const int wr = w >> 1, wc = w & 1;

    const float* Ar = inp + ((size_t)(z * C + ct * 64 + wr * 32 + r)) * S;
    const float* Br = inp + ((size_t)(z * C + cp * 64 + wc * 32 + r)) * S;
    const size_t ROFF = (size_t)16 * S;

    f32x4 acc[2][2];
    #pragma unroll
    for (int i = 0; i < 2; ++i)
        #pragma unroll
        for (int j = 0; j < 2; ++j) acc[i][j] = (f32x4){0.f, 0.f, 0.f, 0.f};
    float rs0 = 0.f, rs1 = 0.f;

    const int sbeg = sp * (S / GSPLIT);
    for (int s0 = sbeg; s0 < sbeg + (S / GSPLIT); s0 += 32) {
        bf16x8 a[2], b[2];
        {
            float4 f0 = *(const float4*)&Ar[s0 + g * 8];
            float4 f1 = *(const float4*)&Ar[s0 + g * 8 + 4];
            a[0] = pack8(f0, f1);
            if (diag && wc == 0)
                rs0 += f0.x + f0.y + f0.z + f0.w + f1.x + f1.y + f1.z + f1.w;
            float4 f2 = *(const float4*)&Ar[ROFF + s0 + g * 8];
            float4 f3 = *(const float4*)&Ar[ROFF + s0 + g * 8 + 4];
            a[1] = pack8(f2, f3);
            if (diag && wc == 0)
                rs1 += f2.x + f2.y + f2.z + f2.w + f3.x + f3.y + f3.z + f3.w;
        }
        {
            float4 f0 = *(const float4*)&Br[s0 + g * 8];
            float4 f1 = *(const float4*)&Br[s0 + g * 8 + 4];
            b[0] = pack8(f0, f1);
            float4 f2 = *(const float4*)&Br[ROFF + s0 + g * 8];
            float4 f3 = *(const float4*)&Br[ROFF + s0 + g * 8 + 4];
            b[1] = pack8(f2, f3);
        }
        #pragma unroll
        for (int i = 0; i < 2; ++i)
            #pragma unroll
            for (int j = 0; j < 2; ++j)
                acc[i][j] = __builtin_amdgcn_mfma_f32_16x16x32_bf16(a[i], b[j], acc[i][j], 0, 0, 0);
    }

    float* Gxz = Gx + (size_t)z * 65536;
    #pragma unroll
    for (int i = 0; i < 2; ++i)
        #pragma unroll
        for (int q = 0; q < 4; ++q) {
            const int row = ct * 64 + wr * 32 + i * 16 + g * 4 + q;
            #pragma unroll
            for (int j = 0; j < 2; ++j) {
                const int col = cp * 64 + wc * 32 + j * 16 + r;
                atomicAdd(&Gxz[(size_t)row * 256 + col], acc[i][j][q]);
                if (!diag) atomicAdd(&Gxz[(size_t)col * 256 + row], acc[i][j][q]);
            }
        }
    if (diag && wc == 0) {
        rs0 += __shfl_xor(rs0, 16, 64); rs0 += __shfl_xor(rs0, 32, 64);
        rs1 += __shfl_xor(rs1, 16, 64); rs1 += __shfl_xor(rs1, 32, 64);
        if (l < 16) {
            atomicAdd(&rx[z * 256 + ct * 64 + wr * 32 + l], rs0);
            atomicAdd(&rx[z * 256 + ct * 64 + wr * 32 + 16 + l], rs1);
        }
    }
}

// ---------------- prep_g: per-block bn recompute + Gb build ----------------
// grid 64: z = bid>>3, rowgroup rg = bid&7 (32 rows each)
__global__ __launch_bounds__(256)
void prep_g(const float* __restrict__ Gx, const float* __restrict__ rx,
            const float* __restrict__ gamma, const float* __restrict__ beta,
            u16* __restrict__ Gb) {
    const int z = blockIdx.x >> 3, rg = blockIdx.x & 7;
    const int t = threadIdx.x;
    __shared__ float scs[256], shs[256], rxl[256];
    {
        float s = 0.f, q = 0.f;
        #pragma unroll
        for (int z2 = 0; z2 < NB; ++z2) {
            s += rx[z2 * 256 + t];
            q += Gx[(size_t)z2 * 65536 + (size_t)t * 257];
        }
        const float invN = 1.0f / (float)(NB * S);
        float m = s * invN;
        float var = q * invN - m * m;
        float rstd = rsqrtf(var + EPS);
        float sc = gamma[t] * rstd;
        scs[t] = sc;
        shs[t] = beta[t] - m * sc;
        rxl[t] = rx[z * 256 + t];
    }
    __syncthreads();
    const int row = rg * 32 + (t >> 3);
    const float scr = scs[row], shr = shs[row], rxr = rxl[row];
    const float* gr = Gx + (size_t)z * 65536 + (size_t)row * 256;
    u16* gb = Gb + (size_t)z * 65536 + (size_t)row * 256;
    #pragma unroll
    for (int it = 0; it < 4; ++it) {
        const int col = it * 64 + (t & 7) * 8;
        float4 g0 = *(const float4*)&gr[col];
        float4 g1 = *(const float4*)&gr[col + 4];
        u16 o[8];
        #pragma unroll
        for (int e = 0; e < 8; ++e) {
            const int cp = col + e;
            const float gx = (e < 4) ? (&g0.x)[e] : (&g1.x)[e - 4];
            float v = scr * scs[cp] * gx + scr * shs[cp] * rxr
                    + shr * scs[cp] * rxl[cp] + 9216.f * shr * shs[cp];
            o[e] = cvt1(v);
        }
        *(uint4*)&gb[col] = *(uint4*)o;
    }
}

// ---------------- prep_v: per-z vectors u, pv (+ z0: sc_sh, p1) ----------------
__global__ __launch_bounds__(256)
void prep_v(const float* __restrict__ Gx, const float* __restrict__ rx,
            const float* __restrict__ gamma, const float* __restrict__ beta,
            const u16* __restrict__ wkT, const u16* __restrict__ Wpv,
            const u16* __restrict__ wpT, const float* __restrict__ b_qkv,
            float* __restrict__ sc_sh, float* __restrict__ uvec,
            float* __restrict__ pvec, float* __restrict__ p1) {
    const int z = blockIdx.x, t = threadIdx.x;
    __shared__ float rsn[256], bvl[256];
    float sc, sh;
    {
        float s = 0.f, q = 0.f;
        #pragma unroll
        for (int z2 = 0; z2 < NB; ++z2) {
            s += rx[z2 * 256 + t];
            q += Gx[(size_t)z2 * 65536 + (size_t)t * 257];
        }
        const float invN = 1.0f / (float)(NB * S);
        float m = s * invN;
        float var = q * invN - m * m;
        float rstd = rsqrtf(var + EPS);
        sc = gamma[t] * rstd;
        sh = beta[t] - m * sc;
        rsn[t] = sc * rx[z * 256 + t] + 9216.f * sh;
        bvl[t] = b_qkv[512 + t];
    }
    __syncthreads();
    float au = 0.f, ap = 0.f;
    const u16* krow = wkT + (size_t)t * 256;
    const u16* prow = Wpv + (size_t)t * 256;
    for (int cb = 0; cb < 256; cb += 8) {
        uint4 kp = *(const uint4*)&krow[cb];
        uint4 pp = *(const uint4*)&prow[cb];
        const u16* kk = (const u16*)&kp;
        const u16* qq = (const u16*)&pp;
        #pragma unroll
        for (int u = 0; u < 8; ++u) {
            au = fmaf(bf2f(kk[u]), rsn[cb + u], au);
            ap = fmaf(bf2f(qq[u]), rsn[cb + u], ap);
        }
    }
    uvec[z * 256 + t] = au;
    pvec[z * 256 + t] = ap;
    if (z == 0) {
        sc_sh[t] = sc;
        sc_sh[C + t] = sh;
        float a1 = 0.f;
        const u16* wrow = wpT + (size_t)t * 256;
        for (int cb = 0; cb < 256; cb += 8) {
            uint4 wp = *(const uint4*)&wrow[cb];
            const u16* ww = (const u16*)&wp;
            #pragma unroll
            for (int u = 0; u < 8; ++u) a1 = fmaf(bf2f(ww[u]), bvl[cb + u], a1);
        }
        p1[t] = a1;
    }
}

// ---------------- t1: T1[z][o][c] = sum_c' Wpv[o][c'] * Gb[z][c][c'] ----------------
// 128 blocks = 8z x 16 tiles(64^2); direct-frag
__global__ __launch_bounds__(256)
void t1_gemm(const u16* __restrict__ Wpv, const u16* __restrict__ Gb,
             u16* __restrict__ T1) {
    const int bid = blockIdx.x;
    const int wid = (bid & 7) * 16 + (bid >> 3);
    const int z = wid >> 4, ot = (wid >> 2) & 3, ct = wid & 3;
    const int tid = threadIdx.x;
    const int w = tid >> 6, l = tid & 63, g = l >> 4, r = l & 15;
    const int wr = w >> 1, wc = w & 1;
    const int mb = ot * 64 + wr * 32, nb = ct * 64 + wc * 32;
    const u16* Gz = Gb + (size_t)z * 65536;

    f32x4 acc[2][2];
    #pragma unroll
    for (int i = 0; i < 2; ++i)
        #pragma unroll
        for (int j = 0; j < 2; ++j) acc[i][j] = (f32x4){0.f, 0.f, 0.f, 0.f};

    for (int k0 = 0; k0 < 256; k0 += 32) {
        bf16x8 a[2], b[2];
        #pragma unroll
        for (int i = 0; i < 2; ++i)
            a[i] = *(const bf16x8*)&Wpv[(size_t)(mb + i * 16 + r) * 256 + k0 + g * 8];
        #pragma unroll
        for (int j = 0; j < 2; ++j)
            b[j] = *(const bf16x8*)&Gz[(size_t)(nb + j * 16 + r) * 256 + k0 + g * 8];
        #pragma unroll
        for (int i = 0; i < 2; ++i)
            #pragma unroll
            for (int j = 0; j < 2; ++j)
                acc[i][j] = __builtin_amdgcn_mfma_f32_16x16x32_bf16(a[i], b[j], acc[i][j], 0, 0, 0);
    }
    u16* Tz = T1 + (size_t)z * 65536;
    #pragma unroll
    for (int i = 0; i < 2; ++i)
        #pragma unroll
        for (int q = 0; q < 4; ++q) {
            const int row = mb + i * 16 + g * 4 + q;
            #pragma unroll
            for (int j = 0; j < 2; ++j)
                Tz[(size_t)row * 256 + nb + j * 16 + r] = cvt1(acc[i][j][q]);
        }
}

// ---------------- ac2: Ac2[z][o][d] = sum_c T1[o][c]*wkT[d][c] + rank-1 terms ----------------
__global__ __launch_bounds__(256)
void ac2_gemm(const u16* __restrict__ T1, const u16* __restrict__ wkT,
              const float* __restrict__ uvec, const float* __restrict__ pvec,
              const float* __restrict__ p1, const float* __restrict__ b_qkv,
              u16* __restrict__ Ac2) {
    const int bid = blockIdx.x;
    const int wid = (bid & 7) * 16 + (bid >> 3);
    const int z = wid >> 4, ot = (wid >> 2) & 3, ct = wid & 3;
    const int tid = threadIdx.x;
    const int w = tid >> 6, l = tid & 63, g = l >> 4, r = l & 15;
    const int wr = w >> 1, wc = w & 1;
    const int mb = ot * 64 + wr * 32, nb = ct * 64 + wc * 32;
    const u16* Tz = T1 + (size_t)z * 65536;

    f32x4 acc[2][2];
    #pragma unroll
    for (int i = 0; i < 2; ++i)
        #pragma unroll
        for (int j = 0; j < 2; ++j) acc[i][j] = (f32x4){0.f, 0.f, 0.f, 0.f};

    for (int k0 = 0; k0 < 256; k0 += 32) {
        bf16x8 a[2], b[2];
        #pragma unroll
        for (int i = 0; i < 2; ++i)
            a[i] = *(const bf16x8*)&Tz[(size_t)(mb + i * 16 + r) * 256 + k0 + g * 8];
        #pragma unroll
        for (int j = 0; j < 2; ++j)
            b[j] = *(const bf16x8*)&wkT[(size_t)(nb + j * 16 + r) * 256 + k0 + g * 8];
        #pragma unroll
        for (int i = 0; i < 2; ++i)
            #pragma unroll
            for (int j = 0; j < 2; ++j)
                acc[i][j] = __builtin_amdgcn_mfma_f32_16x16x32_bf16(a[i], b[j], acc[i][j], 0, 0, 0);
    }
    u16* Az = Ac2 + (size_t)z * 65536;
    #pragma unroll
    for (int i = 0; i < 2; ++i)
        #pragma unroll
        for (int q = 0; q < 4; ++q) {
            const int row = mb + i * 16 + g * 4 + q;
            const float p1r = p1[row];
            const float pvr = pvec[z * 256 + row];
            #pragma unroll
            for (int j = 0; j < 2; ++j) {
                const int col = nb + j * 16 + r;
                const float bkv = b_qkv[256 + col];
                const float uv = uvec[z * 256 + col];
                float v = acc[i][j][q] + p1r * (uv + 9216.f * bkv) + pvr * bkv;
                Az[(size_t)row * 256 + col] = cvt1(v);
            }
        }
}

// ---------------- m: M[z][o][c] = Wpv[o][c] + sum_d Ac2[o][d]*wq[c][d]; ct==0 also constz ----------------
__global__ __launch_bounds__(256)
void m_gemm(const u16* __restrict__ Ac2, const float* __restrict__ w_qkv,
            const u16* __restrict__ Wpv, const float* __restrict__ p1,
            const float* __restrict__ b_qkv, const float* __restrict__ b_proj,
            u16* __restrict__ M, float* __restrict__ constz) {
    const int bid = blockIdx.x;
    const int wid = (bid & 7) * 16 + (bid >> 3);
    const int z = wid >> 4, ot = (wid >> 2) & 3, ct = wid & 3;
    const int tid = threadIdx.x;
    const int w = tid >> 6, l = tid & 63, g = l >> 4, r = l & 15;
    const int wr = w >> 1, wc = w & 1;
    const int mb = ot * 64 + wr * 32, nb = ct * 64 + wc * 32;
    const u16* Az = Ac2 + (size_t)z * 65536;
    const bool docz = (wc == 0 && ct == 0);

    f32x4 acc[2][2];
    #pragma unroll
    for (int i = 0; i < 2; ++i)
        #pragma unroll
        for (int j = 0; j < 2; ++j) acc[i][j] = (f32x4){0.f, 0.f, 0.f, 0.f};
    float cacc[2] = {0.f, 0.f};

    for (int k0 = 0; k0 < 256; k0 += 32) {
        bf16x8 a[2], b[2];
        #pragma unroll
        for (int i = 0; i < 2; ++i)
            a[i] = *(const bf16x8*)&Az[(size_t)(mb + i * 16 + r) * 256 + k0 + g * 8];
        #pragma unroll
        for (int j = 0; j < 2; ++j) {
            const float* p = w_qkv + (size_t)(nb + j * 16 + r) * 768 + k0 + g * 8;
            b[j] = pack8(*(const float4*)p, *(const float4*)(p + 4));
        }
        if (docz) {
            float4 q0 = *(const float4*)&b_qkv[k0 + g * 8];
            float4 q1 = *(const float4*)&b_qkv[k0 + g * 8 + 4];
            float bqv[8] = {q0.x, q0.y, q0.z, q0.w, q1.x, q1.y, q1.z, q1.w};
            #pragma unroll
            for (int i = 0; i < 2; ++i) {
                bf16x8 av = a[i];
                #pragma unroll
                for (int u = 0; u < 8; ++u)
                    cacc[i] = fmaf(bf2f((u16)av[u]), bqv[u], cacc[i]);
            }
        }
        #pragma unroll
        for (int i = 0; i < 2; ++i)
            #pragma unroll
            for (int j = 0; j < 2; ++j)
                acc[i][j] = __builtin_amdgcn_mfma_f32_16x16x32_bf16(a[i], b[j], acc[i][j], 0, 0, 0);
    }
    u16* Mz = M + (size_t)z * 65536;
    #pragma unroll
    for (int i = 0; i < 2; ++i)
        #pragma unroll
        for (int q = 0; q < 4; ++q) {
            const int row = mb + i * 16 + g * 4 + q;
            #pragma unroll
            for (int j = 0; j < 2; ++j) {
                const int col = nb + j * 16 + r;
                float v = acc[i][j][q] + bf2f(Wpv[(size_t)row * 256 + col]);
                Mz[(size_t)row * 256 + col] = cvt1(v);
            }
        }
    if (docz) {
        #pragma unroll
        for (int i = 0; i < 2; ++i) {
            float rr = cacc[i];
            rr += __shfl_xor(rr, 16, 64);
            rr += __shfl_xor(rr, 32, 64);
            if (l < 16) {
                const int o = mb + i * 16 + l;
                constz[z * 256 + o] = b_proj[o] + p1[o] + rr;
            }
        }
    }
}

// ---------------- out: OUT[o][s] = M[o][:] . xn[:][s] + constz[o] + inp[o][s] ----------------
__global__ __launch_bounds__(256)
void out_gemm(const u16* __restrict__ M, const float* __restrict__ inp,
              const float* __restrict__ sc_sh, const float* __restrict__ constz,
              float* __restrict__ out) {
    __shared__ u16 Bsm[128 * LDST];
    const int bid = blockIdx.x;
    const int wid = (bid & 7) * 144 + (bid >> 3);   // 1152 = 8*144
    const int ot = wid & 1;
    const int st = (wid >> 1) % 72;
    const int z  = wid / 144;

    const int tid = threadIdx.x;
    const int l = tid & 63, w = tid >> 6;
    const int m0 = (w >> 1) * 64, n0 = (w & 1) * 64;
    const int g = l >> 4, r = l & 15;
    const int rowL = tid & 127;
    const int half = (tid >> 7) * 16;

    const u16* Mrow = M + (size_t)z * 65536 + (size_t)(ot * 128) * 256;
    const float* inpz = inp + (size_t)z * C * S + (size_t)st * 128 + rowL;

    f32x4 acc[4][4];
    #pragma unroll
    for (int i = 0; i < 4; ++i)
        #pragma unroll
        for (int j = 0; j < 4; ++j) acc[i][j] = (f32x4){0.f, 0.f, 0.f, 0.f};

    for (int k0 = 0; k0 < 256; k0 += 32) {
        {   // B: fused BN + transpose: XN^T tile [128 s][32 c]
            u32 pk[8];
            #pragma unroll
            for (int u = 0; u < 8; ++u) {
                const int c = k0 + half + u * 2;
                float x0 = inpz[(size_t)c * S];
                float x1 = inpz[(size_t)(c + 1) * S];
                u16 b0 = cvt1(fmaf(x0, sc_sh[c], sc_sh[C + c]));
                u16 b1 = cvt1(fmaf(x1, sc_sh[c + 1], sc_sh[C + c + 1]));
                pk[u] = (u32)b0 | ((u32)b1 << 16);
            }
            uint4 q0, q1;
            q0.x = pk[0]; q0.y = pk[1]; q0.z = pk[2]; q0.w = pk[3];
            q1.x = pk[4]; q1.y = pk[5]; q1.z = pk[6]; q1.w = pk[7];
            *(uint4*)&Bsm[rowL * LDST + half] = q0;
            *(uint4*)&Bsm[rowL * LDST + half + 8] = q1;
        }
        __syncthreads();
        bf16x8 a[4], b[4];
        #pragma unroll
        for (int i = 0; i < 4; ++i)
            a[i] = *(const bf16x8*)&Mrow[(size_t)(m0 + i * 16 + r) * 256 + k0 + g * 8];
        #pragma unroll
        for (int j = 0; j < 4; ++j) b[j] = *(const bf16x8*)&Bsm[(n0 + j * 16 + r) * LDST + g * 8];
        #pragma unroll
        for (int i = 0; i < 4; ++i)
            #pragma unroll
            for (int j = 0; j < 4; ++j)
                acc[i][j] = __builtin_amdgcn_mfma_f32_16x16x32_bf16(a[i], b[j], acc[i][j], 0, 0, 0);
        __syncthreads();
    }
    #pragma unroll
    for (int i = 0; i < 4; ++i) {
        #pragma unroll
        for (int q = 0; q < 4; ++q) {
            const int o = ot * 128 + m0 + i * 16 + g * 4 + q;
            const float cz = constz[z * 256 + o];
            const size_t base = ((size_t)z * C + o) * S + st * 128;
            #pragma unroll
            for (int j = 0; j < 4; ++j) {
                const int sl = n0 + j * 16 + r;
                out[base + sl] = acc[i][j][q] + cz + inp[base + sl];
            }
        }
    }
}

extern "C" void kernel_launch(void* const* d_in, const int* in_sizes, int n_in,
                              void* d_out, int out_size, void* d_ws, size_t ws_size,
                              hipStream_t stream) {
    const float* inp    = (const float*)d_in[0];
    const float* gamma  = (const float*)d_in[1];
    const float* beta   = (const float*)d_in[2];
    const float* w_qkv  = (const float*)d_in[3];
    const float* b_qkv  = (const float*)d_in[4];
    const float* w_proj = (const float*)d_in[5];
    const float* b_proj = (const float*)d_in[6];
    float* out = (float*)d_out;

    char* ws = (char*)d_ws;
    float* sc_sh = (float*)(ws + WS_SC);
    float* rx    = (float*)(ws + WS_RX);
    float* uvec  = (float*)(ws + WS_U);
    float* pvec  = (float*)(ws + WS_PV);
    float* p1    = (float*)(ws + WS_P1);
    float* cz    = (float*)(ws + WS_CZ);
    u16*   wkT   = (u16*)(ws + WS_WKT);
    u16*   wpT   = (u16*)(ws + WS_WPT);
    u16*   Wpv   = (u16*)(ws + WS_WPV);
    float* Gx    = (float*)(ws + WS_GX);
    u16*   Gb    = (u16*)(ws + WS_GB);
    u16*   T1    = (u16*)(ws + WS_T1);
    u16*   Ac2   = (u16*)(ws + WS_AC2);
    u16*   Mm    = (u16*)(ws + WS_M);

    hipMemsetAsync(Gx, 0, (size_t)NB * 65536 * sizeof(float), stream);
    hipMemsetAsync(rx, 0, (size_t)NB * 256 * sizeof(float), stream);

    wt_build<<<dim3(512), dim3(256), 0, stream>>>(w_qkv, w_proj, wkT, wpT);
    wpv_gemm<<<dim3(16), dim3(256), 0, stream>>>(wpT, w_qkv, Wpv);
    gram<<<dim3(960), dim3(256), 0, stream>>>(inp, Gx, rx);
    prep_g<<<dim3(64), dim3(256), 0, stream>>>(Gx, rx, gamma, beta, Gb);
    prep_v<<<dim3(NB), dim3(256), 0, stream>>>(Gx, rx, gamma, beta, wkT, Wpv, wpT,
                                               b_qkv, sc_sh, uvec, pvec, p1);
    t1_gemm<<<dim3(128), dim3(256), 0, stream>>>(Wpv, Gb, T1);
    ac2_gemm<<<dim3(128), dim3(256), 0, stream>>>(T1, wkT, uvec, pvec, p1, b_qkv, Ac2);
    m_gemm<<<dim3(128), dim3(256), 0, stream>>>(Ac2, w_qkv, Wpv, p1, b_qkv, b_proj, Mm, cz);
    out_gemm<<<dim3(1152), dim3(256), 0, stream>>>(Mm, inp, sc_sh, cz, out);
}

// Round 7
// 194.162 us; speedup vs baseline: 5.4962x; 1.1731x over previous
//
#include <hip/hip_runtime.h>
#include <hip/hip_bf16.h>
#include <stdint.h>

#define S 9216
#define C 256
#define NB 8
#define EPS 1e-5f
#define LDST 40    // LDS row stride (u16) for out_gemm B tile
#define GSPL 18    // s-splits in gram (512 s each)
#define GLD 144    // gram LDS row stride in u16

typedef __attribute__((ext_vector_type(8))) short bf16x8;
typedef __attribute__((ext_vector_type(4))) float f32x4;
typedef unsigned short u16;
typedef unsigned int u32;

// ---------------- ws layout (bytes) ----------------
#define WS_SC   0          // sc_sh fp32 [512]
#define WS_RX   4096       // rx fp32 [8][256]
#define WS_DS   16384      // diagS fp32 [256]
#define WS_U    20480      // uvec fp32 [8][256]
#define WS_PV   32768      // pvec fp32 [8][256]
#define WS_P1   45056      // p1 fp32 [256]
#define WS_CZ   49152      // constz fp32 [8][256]
#define WS_WKT  65536      // wkT bf16 [256][256]
#define WS_WPT  196608     // wpT bf16 [256][256]
#define WS_WPV  327680     // Wpv bf16 [256][256]
#define WS_GB   458752     // Gb bf16 [8][256][256]
#define WS_T1   1507328    // T1 bf16 [8][256][256]
#define WS_AC2  2555904    // Ac2 bf16 [8][256][256]
#define WS_M    3604480    // M bf16 [8][256][256]
#define WS_P    4718592    // partials fp32 [8][10][18][64][64] = 23.6MB

__device__ __forceinline__ float bf2f(u16 b) { return __uint_as_float((u32)b << 16); }
__device__ __forceinline__ u16 cvt1(float x) {
    __hip_bfloat16 h = __float2bfloat16(x);
    return *(u16*)&h;
}
__device__ __forceinline__ bf16x8 pack8(float4 a, float4 b) {
    union { bf16x8 v; u16 h[8]; } u;
    u.h[0] = cvt1(a.x); u.h[1] = cvt1(a.y); u.h[2] = cvt1(a.z); u.h[3] = cvt1(a.w);
    u.h[4] = cvt1(b.x); u.h[5] = cvt1(b.y); u.h[6] = cvt1(b.z); u.h[7] = cvt1(b.w);
    return u.v;
}
__device__ __forceinline__ void tile_enum(int tile, int& ti, int& tj) {
    if (tile < 4) { ti = tile; tj = tile; }
    else {
        const int u = tile - 4;
        ti = (u < 3) ? 0 : ((u < 5) ? 1 : 2);
        tj = (u < 3) ? (u + 1) : ((u < 5) ? (u - 1) : 3);
    }
}

// ---------------- weight transposes ----------------
__global__ __launch_bounds__(256)
void wt_build(const float* __restrict__ w_qkv, const float* __restrict__ w_proj,
              u16* __restrict__ wkT, u16* __restrict__ wpT) {
    const int r0 = blockIdx.x, c = threadIdx.x;
    if (r0 < 256) {
        wkT[(size_t)r0 * 256 + c] = cvt1(w_qkv[(size_t)c * 768 + 256 + r0]);
    } else {
        const int o = r0 - 256;
        wpT[(size_t)o * 256 + c] = cvt1(w_proj[(size_t)c * 256 + o]);
    }
}

// ---------------- Wpv[o][c] = sum_e wpT[o][e] * w_qkv[c][512+e] ----------------
__global__ __launch_bounds__(256)
void wpv_gemm(const u16* __restrict__ wpT, const float* __restrict__ w_qkv,
              u16* __restrict__ Wpv) {
    const int bid = blockIdx.x;
    const int ot = bid >> 2, ct = bid & 3;
    const int tid = threadIdx.x;
    const int w = tid >> 6, l = tid & 63, g = l >> 4, r = l & 15;
    const int wr = w >> 1, wc = w & 1;
    const int mb = ot * 64 + wr * 32, nb = ct * 64 + wc * 32;

    f32x4 acc[2][2];
    #pragma unroll
    for (int i = 0; i < 2; ++i)
        #pragma unroll
        for (int j = 0; j < 2; ++j) acc[i][j] = (f32x4){0.f, 0.f, 0.f, 0.f};

    for (int k0 = 0; k0 < 256; k0 += 32) {
        bf16x8 a[2], b[2];
        #pragma unroll
        for (int i = 0; i < 2; ++i)
            a[i] = *(const bf16x8*)&wpT[(size_t)(mb + i * 16 + r) * 256 + k0 + g * 8];
        #pragma unroll
        for (int j = 0; j < 2; ++j) {
            const float* p = w_qkv + (size_t)(nb + j * 16 + r) * 768 + 512 + k0 + g * 8;
            b[j] = pack8(*(const float4*)p, *(const float4*)(p + 4));
        }
        #pragma unroll
        for (int i = 0; i < 2; ++i)
            #pragma unroll
            for (int j = 0; j < 2; ++j)
                acc[i][j] = __builtin_amdgcn_mfma_f32_16x16x32_bf16(a[i], b[j], acc[i][j], 0, 0, 0);
    }
    #pragma unroll
    for (int i = 0; i < 2; ++i)
        #pragma unroll
        for (int q = 0; q < 4; ++q) {
            const int row = mb + i * 16 + g * 4 + q;
            #pragma unroll
            for (int j = 0; j < 2; ++j)
                Wpv[(size_t)row * 256 + nb + j * 16 + r] = cvt1(acc[i][j][q]);
        }
}

// ---------------- gram_part: per-(z,tile,split) 64x64 partial, NO Gx atomics ----------------
// coalesced staging: each wave-instruction reads one full 128-float row chunk (float2/lane)
__global__ __launch_bounds__(256)
void gram_part(const float* __restrict__ inp, float* __restrict__ P, float* __restrict__ rx) {
    __shared__ u16 Lsm[128 * GLD];
    const int bid = blockIdx.x;
    const int wid = (bid & 7) * 180 + (bid >> 3);   // 1440 = 8*180
    const int z = wid / 180;
    const int rem = wid % 180;
    const int tile = rem / GSPL;
    const int sp = rem % GSPL;
    int ti, tj; tile_enum(tile, ti, tj);
    const bool diag = (ti == tj);

    const int tid = threadIdx.x;
    const int w = tid >> 6, l = tid & 63;
    const int g = l >> 4, r = l & 15;
    const int wr = w >> 1, wc = w & 1;

    const float* Abase = inp + ((size_t)(z * C + ti * 64)) * S;
    const float* Bbase = inp + ((size_t)(z * C + tj * 64)) * S;

    f32x4 acc[2][2];
    #pragma unroll
    for (int i = 0; i < 2; ++i)
        #pragma unroll
        for (int j = 0; j < 2; ++j) acc[i][j] = (f32x4){0.f, 0.f, 0.f, 0.f};
    float rsA[16];
    #pragma unroll
    for (int rr = 0; rr < 16; ++rr) rsA[rr] = 0.f;

    const int sbeg = sp * 512;
    for (int it = 0; it < 4; ++it) {
        const int s0 = sbeg + it * 128;
        __syncthreads();
        // stage A rows (wave w: rows w*16 .. +16), one row per instruction, contiguous 512B
        #pragma unroll
        for (int rr = 0; rr < 16; ++rr) {
            const int row = w * 16 + rr;
            float2 f = *(const float2*)&Abase[(size_t)row * S + s0 + l * 2];
            u32 pk = (u32)cvt1(f.x) | ((u32)cvt1(f.y) << 16);
            *(u32*)&Lsm[row * GLD + l * 2] = pk;
            if (diag) {
                float rs = f.x + f.y;
                rs += __shfl_xor(rs, 1);  rs += __shfl_xor(rs, 2);
                rs += __shfl_xor(rs, 4);  rs += __shfl_xor(rs, 8);
                rs += __shfl_xor(rs, 16); rs += __shfl_xor(rs, 32);
                rsA[rr] += rs;
            }
        }
        if (!diag) {
            #pragma unroll
            for (int rr = 0; rr < 16; ++rr) {
                const int row = w * 16 + rr;
                float2 f = *(const float2*)&Bbase[(size_t)row * S + s0 + l * 2];
                u32 pk = (u32)cvt1(f.x) | ((u32)cvt1(f.y) << 16);
                *(u32*)&Lsm[(64 + row) * GLD + l * 2] = pk;
            }
        }
        __syncthreads();
        const int bb = diag ? 0 : 64;
        #pragma unroll
        for (int k0 = 0; k0 < 128; k0 += 32) {
            bf16x8 a[2], b[2];
            #pragma unroll
            for (int i = 0; i < 2; ++i)
                a[i] = *(const bf16x8*)&Lsm[(wr * 32 + i * 16 + r) * GLD + k0 + g * 8];
            #pragma unroll
            for (int j = 0; j < 2; ++j)
                b[j] = *(const bf16x8*)&Lsm[(bb + wc * 32 + j * 16 + r) * GLD + k0 + g * 8];
            #pragma unroll
            for (int i = 0; i < 2; ++i)
                #pragma unroll
                for (int j = 0; j < 2; ++j)
                    acc[i][j] = __builtin_amdgcn_mfma_f32_16x16x32_bf16(a[i], b[j], acc[i][j], 0, 0, 0);
        }
    }
    float* PP = P + (((size_t)(z * 10 + tile) * GSPL + sp) << 12);
    #pragma unroll
    for (int i = 0; i < 2; ++i)
        #pragma unroll
        for (int q = 0; q < 4; ++q) {
            const int row = wr * 32 + i * 16 + g * 4 + q;
            #pragma unroll
            for (int j = 0; j < 2; ++j)
                PP[row * 64 + wc * 32 + j * 16 + r] = acc[i][j][q];
        }
    if (diag && l == 0) {
        #pragma unroll
        for (int rr = 0; rr < 16; ++rr)
            atomicAdd(&rx[z * 256 + ti * 64 + w * 16 + rr], rsA[rr]);
    }
}

// ---------------- red_diag: diagS[c] = sum_{z,sp} P[z][c>>6][sp][(c&63)*65] ----------------
__global__ __launch_bounds__(256)
void red_diag(const float* __restrict__ P, float* __restrict__ diagS) {
    const int c = threadIdx.x;
    const int pp = blockIdx.x;   // 36
    float s = 0.f;
    #pragma unroll
    for (int k = 0; k < 4; ++k) {
        const int pair = pp * 4 + k;        // 0..143 = 8z * 18sp
        const int zz = pair / GSPL, sp2 = pair % GSPL;
        s += P[(((size_t)(zz * 10 + (c >> 6)) * GSPL + sp2) << 12) + (size_t)(c & 63) * 65];
    }
    atomicAdd(&diagS[c], s);
}

// ---------------- bn_fin: sc_sh from diagS + rx ----------------
__global__ __launch_bounds__(256)
void bn_fin(const float* __restrict__ diagS, const float* __restrict__ rx,
            const float* __restrict__ gamma, const float* __restrict__ beta,
            float* __restrict__ sc_sh) {
    const int c = threadIdx.x;
    float s = 0.f;
    #pragma unroll
    for (int z = 0; z < NB; ++z) s += rx[z * 256 + c];
    const float q = diagS[c];
    const float invN = 1.0f / (float)(NB * S);
    float m = s * invN;
    float var = q * invN - m * m;
    float rstd = rsqrtf(var + EPS);
    float sc = gamma[c] * rstd;
    sc_sh[c] = sc;
    sc_sh[C + c] = beta[c] - m * sc;
}

// ---------------- prep_g2: Gb from partial sums + affine; symmetric dual write ----------------
__global__ __launch_bounds__(256)
void prep_g2(const float* __restrict__ P, const float* __restrict__ rx,
             const float* __restrict__ sc_sh, u16* __restrict__ Gb) {
    __shared__ float scs[256], shs[256], rxl[256];
    __shared__ u16 T[64][66];
    const int bid = blockIdx.x;        // 80
    const int z = bid / 10, tile = bid % 10;
    int ti, tj; tile_enum(tile, ti, tj);
    const int t = threadIdx.x;
    scs[t] = sc_sh[t]; shs[t] = sc_sh[C + t]; rxl[t] = rx[z * 256 + t];
    __syncthreads();
    const int rr = t >> 2, cc = (t & 3) * 16;
    float s[16];
    #pragma unroll
    for (int e = 0; e < 16; ++e) s[e] = 0.f;
    for (int sp = 0; sp < GSPL; ++sp) {
        const float* src = P + (((size_t)(z * 10 + tile) * GSPL + sp) << 12) + rr * 64 + cc;
        #pragma unroll
        for (int e4 = 0; e4 < 4; ++e4) {
            float4 v = *(const float4*)&src[e4 * 4];
            s[e4 * 4 + 0] += v.x; s[e4 * 4 + 1] += v.y;
            s[e4 * 4 + 2] += v.z; s[e4 * 4 + 3] += v.w;
        }
    }
    const int gr = ti * 64 + rr;
    u16 o[16];
    #pragma unroll
    for (int e = 0; e < 16; ++e) {
        const int gc = tj * 64 + cc + e;
        float v = scs[gr] * scs[gc] * s[e] + scs[gr] * shs[gc] * rxl[gr]
                + shs[gr] * scs[gc] * rxl[gc] + 9216.f * shs[gr] * shs[gc];
        o[e] = cvt1(v);
    }
    u16* dst = Gb + (size_t)z * 65536 + (size_t)gr * 256 + tj * 64 + cc;
    *(uint4*)&dst[0] = *(uint4*)&o[0];
    *(uint4*)&dst[8] = *(uint4*)&o[8];
    if (ti != tj) {
        #pragma unroll
        for (int e = 0; e < 16; ++e) T[rr][cc + e] = o[e];
        __syncthreads();
        u16 o2[16];
        #pragma unroll
        for (int e = 0; e < 16; ++e) o2[e] = T[cc + e][rr];
        u16* dst2 = Gb + (size_t)z * 65536 + (size_t)(tj * 64 + rr) * 256 + ti * 64 + cc;
        *(uint4*)&dst2[0] = *(uint4*)&o2[0];
        *(uint4*)&dst2[8] = *(uint4*)&o2[8];
    }
}

// ---------------- prep_v: per-z vectors u, pv (+ z0: p1) ----------------
__global__ __launch_bounds__(256)
void prep_v(const float* __restrict__ sc_sh, const float* __restrict__ rx,
            const u16* __restrict__ wkT, const u16* __restrict__ Wpv,
            const u16* __restrict__ wpT, const float* __restrict__ b_qkv,
            float* __restrict__ uvec, float* __restrict__ pvec, float* __restrict__ p1) {
    const int z = blockIdx.x, t = threadIdx.x;
    __shared__ float rsn[256], bvl[256];
    rsn[t] = sc_sh[t] * rx[z * 256 + t] + 9216.f * sc_sh[C + t];
    bvl[t] = b_qkv[512 + t];
    __syncthreads();
    float au = 0.f, ap = 0.f;
    const u16* krow = wkT + (size_t)t * 256;
    const u16* prow = Wpv + (size_t)t * 256;
    for (int cb = 0; cb < 256; cb += 8) {
        uint4 kp = *(const uint4*)&krow[cb];
        uint4 pp = *(const uint4*)&prow[cb];
        const u16* kk = (const u16*)&kp;
        const u16* qq = (const u16*)&pp;
        #pragma unroll
        for (int u = 0; u < 8; ++u) {
            au = fmaf(bf2f(kk[u]), rsn[cb + u], au);
            ap = fmaf(bf2f(qq[u]), rsn[cb + u], ap);
        }
    }
    uvec[z * 256 + t] = au;
    pvec[z * 256 + t] = ap;
    if (z == 0) {
        float a1 = 0.f;
        const u16* wrow = wpT + (size_t)t * 256;
        for (int cb = 0; cb < 256; cb += 8) {
            uint4 wp = *(const uint4*)&wrow[cb];
            const u16* ww = (const u16*)&wp;
            #pragma unroll
            for (int u = 0; u < 8; ++u) a1 = fmaf(bf2f(ww[u]), bvl[cb + u], a1);
        }
        p1[t] = a1;
    }
}

// ---------------- t1: T1[z][o][c] = sum_c' Wpv[o][c'] * Gb[z][c][c'] ----------------
__global__ __launch_bounds__(256)
void t1_gemm(const u16* __restrict__ Wpv, const u16* __restrict__ Gb,
             u16* __restrict__ T1) {
    const int bid = blockIdx.x;
    const int wid = (bid & 7) * 16 + (bid >> 3);
    const int z = wid >> 4, ot = (wid >> 2) & 3, ct = wid & 3;
    const int tid = threadIdx.x;
    const int w = tid >> 6, l = tid & 63, g = l >> 4, r = l & 15;
    const int wr = w >> 1, wc = w & 1;
    const int mb = ot * 64 + wr * 32, nb = ct * 64 + wc * 32;
    const u16* Gz = Gb + (size_t)z * 65536;

    f32x4 acc[2][2];
    #pragma unroll
    for (int i = 0; i < 2; ++i)
        #pragma unroll
        for (int j = 0; j < 2; ++j) acc[i][j] = (f32x4){0.f, 0.f, 0.f, 0.f};

    for (int k0 = 0; k0 < 256; k0 += 32) {
        bf16x8 a[2], b[2];
        #pragma unroll
        for (int i = 0; i < 2; ++i)
            a[i] = *(const bf16x8*)&Wpv[(size_t)(mb + i * 16 + r) * 256 + k0 + g * 8];
        #pragma unroll
        for (int j = 0; j < 2; ++j)
            b[j] = *(const bf16x8*)&Gz[(size_t)(nb + j * 16 + r) * 256 + k0 + g * 8];
        #pragma unroll
        for (int i = 0; i < 2; ++i)
            #pragma unroll
            for (int j = 0; j < 2; ++j)
                acc[i][j] = __builtin_amdgcn_mfma_f32_16x16x32_bf16(a[i], b[j], acc[i][j], 0, 0, 0);
    }
    u16* Tz = T1 + (size_t)z * 65536;
    #pragma unroll
    for (int i = 0; i < 2; ++i)
        #pragma unroll
        for (int q = 0; q < 4; ++q) {
            const int row = mb + i * 16 + g * 4 + q;
            #pragma unroll
            for (int j = 0; j < 2; ++j)
                Tz[(size_t)row * 256 + nb + j * 16 + r] = cvt1(acc[i][j][q]);
        }
}

// ---------------- ac2: Ac2[z][o][d] = sum_c T1[o][c]*wkT[d][c] + rank-1 terms ----------------
__global__ __launch_bounds__(256)
void ac2_gemm(const u16* __restrict__ T1, const u16* __restrict__ wkT,
              const float* __restrict__ uvec, const float* __restrict__ pvec,
              const float* __restrict__ p1, const float* __restrict__ b_qkv,
              u16* __restrict__ Ac2) {
    const int bid = blockIdx.x;
    const int wid = (bid & 7) * 16 + (bid >> 3);
    const int z = wid >> 4, ot = (wid >> 2) & 3, ct = wid & 3;
    const int tid = threadIdx.x;
    const int w = tid >> 6, l = tid & 63, g = l >> 4, r = l & 15;
    const int wr = w >> 1, wc = w & 1;
    const int mb = ot * 64 + wr * 32, nb = ct * 64 + wc * 32;
    const u16* Tz = T1 + (size_t)z * 65536;

    f32x4 acc[2][2];
    #pragma unroll
    for (int i = 0; i < 2; ++i)
        #pragma unroll
        for (int j = 0; j < 2; ++j) acc[i][j] = (f32x4){0.f, 0.f, 0.f, 0.f};

    for (int k0 = 0; k0 < 256; k0 += 32) {
        bf16x8 a[2], b[2];
        #pragma unroll
        for (int i = 0; i < 2; ++i)
            a[i] = *(const bf16x8*)&Tz[(size_t)(mb + i * 16 + r) * 256 + k0 + g * 8];
        #pragma unroll
        for (int j = 0; j < 2; ++j)
            b[j] = *(const bf16x8*)&wkT[(size_t)(nb + j * 16 + r) * 256 + k0 + g * 8];
        #pragma unroll
        for (int i = 0; i < 2; ++i)
            #pragma unroll
            for (int j = 0; j < 2; ++j)
                acc[i][j] = __builtin_amdgcn_mfma_f32_16x16x32_bf16(a[i], b[j], acc[i][j], 0, 0, 0);
    }
    u16* Az = Ac2 + (size_t)z * 65536;
    #pragma unroll
    for (int i = 0; i < 2; ++i)
        #pragma unroll
        for (int q = 0; q < 4; ++q) {
            const int row = mb + i * 16 + g * 4 + q;
            const float p1r = p1[row];
            const float pvr = pvec[z * 256 + row];
            #pragma unroll
            for (int j = 0; j < 2; ++j) {
                const int col = nb + j * 16 + r;
                const float bkv = b_qkv[256 + col];
                const float uv = uvec[z * 256 + col];
                float v = acc[i][j][q] + p1r * (uv + 9216.f * bkv) + pvr * bkv;
                Az[(size_t)row * 256 + col] = cvt1(v);
            }
        }
}

// ---------------- m: M[z][o][c] = Wpv[o][c] + sum_d Ac2[o][d]*wq[c][d]; ct==0: constz ----------------
__global__ __launch_bounds__(256)
void m_gemm(const u16* __restrict__ Ac2, const float* __restrict__ w_qkv,
            const u16* __restrict__ Wpv, const float* __restrict__ p1,
            const float* __restrict__ b_qkv, const float* __restrict__ b_proj,
            u16* __restrict__ M, float* __restrict__ constz) {
    const int bid = blockIdx.x;
    const int wid = (bid & 7) * 16 + (bid >> 3);
    const int z = wid >> 4, ot = (wid >> 2) & 3, ct = wid & 3;
    const int tid = threadIdx.x;
    const int w = tid >> 6, l = tid & 63, g = l >> 4, r = l & 15;
    const int wr = w >> 1, wc = w & 1;
    const int mb = ot * 64 + wr * 32, nb = ct * 64 + wc * 32;
    const u16* Az = Ac2 + (size_t)z * 65536;
    const bool docz = (wc == 0 && ct == 0);

    f32x4 acc[2][2];
    #pragma unroll
    for (int i = 0; i < 2; ++i)
        #pragma unroll
        for (int j = 0; j < 2; ++j) acc[i][j] = (f32x4){0.f, 0.f, 0.f, 0.f};
    float cacc[2] = {0.f, 0.f};

    for (int k0 = 0; k0 < 256; k0 += 32) {
        bf16x8 a[2], b[2];
        #pragma unroll
        for (int i = 0; i < 2; ++i)
            a[i] = *(const bf16x8*)&Az[(size_t)(mb + i * 16 + r) * 256 + k0 + g * 8];
        #pragma unroll
        for (int j = 0; j < 2; ++j) {
            const float* p = w_qkv + (size_t)(nb + j * 16 + r) * 768 + k0 + g * 8;
            b[j] = pack8(*(const float4*)p, *(const float4*)(p + 4));
        }
        if (docz) {
            float4 q0 = *(const float4*)&b_qkv[k0 + g * 8];
            float4 q1 = *(const float4*)&b_qkv[k0 + g * 8 + 4];
            float bqv[8] = {q0.x, q0.y, q0.z, q0.w, q1.x, q1.y, q1.z, q1.w};
            #pragma unroll
            for (int i = 0; i < 2; ++i) {
                bf16x8 av = a[i];
                #pragma unroll
                for (int u = 0; u < 8; ++u)
                    cacc[i] = fmaf(bf2f((u16)av[u]), bqv[u], cacc[i]);
            }
        }
        #pragma unroll
        for (int i = 0; i < 2; ++i)
            #pragma unroll
            for (int j = 0; j < 2; ++j)
                acc[i][j] = __builtin_amdgcn_mfma_f32_16x16x32_bf16(a[i], b[j], acc[i][j], 0, 0, 0);
    }
    u16* Mz = M + (size_t)z * 65536;
    #pragma unroll
    for (int i = 0; i < 2; ++i)
        #pragma unroll
        for (int q = 0; q < 4; ++q) {
            const int row = mb + i * 16 + g * 4 + q;
            #pragma unroll
            for (int j = 0; j < 2; ++j) {
                const int col = nb + j * 16 + r;
                float v = acc[i][j][q] + bf2f(Wpv[(size_t)row * 256 + col]);
                Mz[(size_t)row * 256 + col] = cvt1(v);
            }
        }
    if (docz) {
        #pragma unroll
        for (int i = 0; i < 2; ++i) {
            float rr = cacc[i];
            rr += __shfl_xor(rr, 16, 64);
            rr += __shfl_xor(rr, 32, 64);
            if (l < 16) {
                const int o = mb + i * 16 + l;
                constz[z * 256 + o] = b_proj[o] + p1[o] + rr;
            }
        }
    }
}

// ---------------- out: OUT[o][s] = M[o][:] . xn[:][s] + constz[o] + inp[o][s] ----------------
__global__ __launch_bounds__(256)
void out_gemm(const u16* __restrict__ M, const float* __restrict__ inp,
              const float* __restrict__ sc_sh, const float* __restrict__ constz,
              float* __restrict__ out) {
    __shared__ u16 Bsm[128 * LDST];
    const int bid = blockIdx.x;
    const int wid = (bid & 7) * 144 + (bid >> 3);   // 1152 = 8*144
    const int ot = wid & 1;
    const int st = (wid >> 1) % 72;
    const int z  = wid / 144;

    const int tid = threadIdx.x;
    const int l = tid & 63, w = tid >> 6;
    const int m0 = (w >> 1) * 64, n0 = (w & 1) * 64;
    const int g = l >> 4, r = l & 15;
    const int rowL = tid & 127;
    const int half = (tid >> 7) * 16;

    const u16* Mrow = M + (size_t)z * 65536 + (size_t)(ot * 128) * 256;
    const float* inpz = inp + (size_t)z * C * S + (size_t)st * 128 + rowL;

    f32x4 acc[4][4];
    #pragma unroll
    for (int i = 0; i < 4; ++i)
        #pragma unroll
        for (int j = 0; j < 4; ++j) acc[i][j] = (f32x4){0.f, 0.f, 0.f, 0.f};

    for (int k0 = 0; k0 < 256; k0 += 32) {
        {   // B: fused BN + transpose: XN^T tile [128 s][32 c]
            u32 pk[8];
            #pragma unroll
            for (int u = 0; u < 8; ++u) {
                const int c = k0 + half + u * 2;
                float x0 = inpz[(size_t)c * S];
                float x1 = inpz[(size_t)(c + 1) * S];
                u16 b0 = cvt1(fmaf(x0, sc_sh[c], sc_sh[C + c]));
                u16 b1 = cvt1(fmaf(x1, sc_sh[c + 1], sc_sh[C + c + 1]));
                pk[u] = (u32)b0 | ((u32)b1 << 16);
            }
            uint4 q0, q1;
            q0.x = pk[0]; q0.y = pk[1]; q0.z = pk[2]; q0.w = pk[3];
            q1.x = pk[4]; q1.y = pk[5]; q1.z = pk[6]; q1.w = pk[7];
            *(uint4*)&Bsm[rowL * LDST + half] = q0;
            *(uint4*)&Bsm[rowL * LDST + half + 8] = q1;
        }
        __syncthreads();
        bf16x8 a[4], b[4];
        #pragma unroll
        for (int i = 0; i < 4; ++i)
            a[i] = *(const bf16x8*)&Mrow[(size_t)(m0 + i * 16 + r) * 256 + k0 + g * 8];
        #pragma unroll
        for (int j = 0; j < 4; ++j) b[j] = *(const bf16x8*)&Bsm[(n0 + j * 16 + r) * LDST + g * 8];
        #pragma unroll
        for (int i = 0; i < 4; ++i)
            #pragma unroll
            for (int j = 0; j < 4; ++j)
                acc[i][j] = __builtin_amdgcn_mfma_f32_16x16x32_bf16(a[i], b[j], acc[i][j], 0, 0, 0);
        __syncthreads();
    }
    #pragma unroll
    for (int i = 0; i < 4; ++i) {
        #pragma unroll
        for (int q = 0; q < 4; ++q) {
            const int o = ot * 128 + m0 + i * 16 + g * 4 + q;
            const float cz = constz[z * 256 + o];
            const size_t base = ((size_t)z * C + o) * S + st * 128;
            #pragma unroll
            for (int j = 0; j < 4; ++j) {
                const int sl = n0 + j * 16 + r;
                out[base + sl] = acc[i][j][q] + cz + inp[base + sl];
            }
        }
    }
}

extern "C" void kernel_launch(void* const* d_in, const int* in_sizes, int n_in,
                              void* d_out, int out_size, void* d_ws, size_t ws_size,
                              hipStream_t stream) {
    const float* inp    = (const float*)d_in[0];
    const float* gamma  = (const float*)d_in[1];
    const float* beta   = (const float*)d_in[2];
    const float* w_qkv  = (const float*)d_in[3];
    const float* b_qkv  = (const float*)d_in[4];
    const float* w_proj = (const float*)d_in[5];
    const float* b_proj = (const float*)d_in[6];
    float* out = (float*)d_out;

    char* ws = (char*)d_ws;
    float* sc_sh = (float*)(ws + WS_SC);
    float* rx    = (float*)(ws + WS_RX);
    float* diagS = (float*)(ws + WS_DS);
    float* uvec  = (float*)(ws + WS_U);
    float* pvec  = (float*)(ws + WS_PV);
    float* p1    = (float*)(ws + WS_P1);
    float* cz    = (float*)(ws + WS_CZ);
    u16*   wkT   = (u16*)(ws + WS_WKT);
    u16*   wpT   = (u16*)(ws + WS_WPT);
    u16*   Wpv   = (u16*)(ws + WS_WPV);
    u16*   Gb    = (u16*)(ws + WS_GB);
    u16*   T1    = (u16*)(ws + WS_T1);
    u16*   Ac2   = (u16*)(ws + WS_AC2);
    u16*   Mm    = (u16*)(ws + WS_M);
    float* P     = (float*)(ws + WS_P);

    hipMemsetAsync(rx, 0, NB * 256 * sizeof(float), stream);
    hipMemsetAsync(diagS, 0, 256 * sizeof(float), stream);

    wt_build<<<dim3(512), dim3(256), 0, stream>>>(w_qkv, w_proj, wkT, wpT);
    wpv_gemm<<<dim3(16), dim3(256), 0, stream>>>(wpT, w_qkv, Wpv);
    gram_part<<<dim3(1440), dim3(256), 0, stream>>>(inp, P, rx);
    red_diag<<<dim3(36), dim3(256), 0, stream>>>(P, diagS);
    bn_fin<<<dim3(1), dim3(256), 0, stream>>>(diagS, rx, gamma, beta, sc_sh);
    prep_g2<<<dim3(80), dim3(256), 0, stream>>>(P, rx, sc_sh, Gb);
    prep_v<<<dim3(NB), dim3(256), 0, stream>>>(sc_sh, rx, wkT, Wpv, wpT, b_qkv, uvec, pvec, p1);
    t1_gemm<<<dim3(128), dim3(256), 0, stream>>>(Wpv, Gb, T1);
    ac2_gemm<<<dim3(128), dim3(256), 0, stream>>>(T1, wkT, uvec, pvec, p1, b_qkv, Ac2);
    m_gemm<<<dim3(128), dim3(256), 0, stream>>>(Ac2, w_qkv, Wpv, p1, b_qkv, b_proj, Mm, cz);
    out_gemm<<<dim3(1152), dim3(256), 0, stream>>>(Mm, inp, sc_sh, cz, out);
}